// Round 11
// baseline (839.230 us; speedup 1.0000x reference)
//
#include <hip/hip_runtime.h>
#include <hip/hip_bf16.h>
#include <math.h>

// Problem constants
#define BB 2
#define TT 4
#define CIN 128
#define DM 256
#define NQ 300
#define NP 8
#define PS 3
#define NL 6
#define HW 4096   // 64*64
#define KP 2304   // 3*3*256

typedef __attribute__((ext_vector_type(8))) short short8;
typedef __attribute__((ext_vector_type(4))) short short4_t;
typedef __attribute__((ext_vector_type(4))) float f32x4;
typedef unsigned short ushort_t;

static __device__ __forceinline__ ushort_t f2bf(float f) {
  __hip_bfloat16 h = __float2bfloat16(f);
  return *reinterpret_cast<ushort_t*>(&h);
}
static __device__ __forceinline__ float bf2f(ushort_t u) {
  return __uint_as_float(((unsigned)u) << 16);
}

// ---------------------------------------------------------------------------
// ONE mega prep kernel (block-range ladder):
//  [0,3680)       plain fp32->bf16 (w_in|w_lat|w_b1|w_r1|Wp1)
//  [3680,3936)    tct coeffs
//  [3936,4192)    wsm reorder (LDS-staged, coalesced both sides; 1 block/n)
//  [4192,4204)    bqt | bfuse
//  [4204,5293)    zero x2p
//  [5293,5294)    bias_comb
//  [5294,5894)    queries/boxes init
//  [5894,6918)    feat transpose -> featT
__global__ void k_prep(const float* __restrict__ w_in, const float* __restrict__ w_lat,
                       const float* __restrict__ w_b1,
                       const float* __restrict__ w_r1, const float* __restrict__ Wp1,
                       ushort_t* __restrict__ win_bf, ushort_t* __restrict__ wlat_bf,
                       ushort_t* __restrict__ wb1_bf,
                       ushort_t* __restrict__ wr1_bf, ushort_t* __restrict__ wp1_bf,
                       const float* __restrict__ w_tf, ushort_t* __restrict__ tct,
                       const float* __restrict__ w_sm, ushort_t* __restrict__ wsm_bf,
                       const float* __restrict__ Wp2, const float* __restrict__ Wo,
                       const float* __restrict__ bq, const float* __restrict__ bp2,
                       const float* __restrict__ bo,
                       float* __restrict__ bqt, float* __restrict__ bfuse,
                       uint4* __restrict__ x2p_zero,
                       const float* __restrict__ b_tf, const float* __restrict__ b_in,
                       float* __restrict__ bias_comb,
                       const float* __restrict__ qe, const float* __restrict__ qp,
                       const float* __restrict__ pb, float* __restrict__ queries,
                       ushort_t* __restrict__ qbf, float* __restrict__ boxes,
                       const float* __restrict__ feat, ushort_t* __restrict__ featT) {
  __shared__ float ldsF[64][65];
  float* bt = &ldsF[0][0];
  int b = blockIdx.x, t = threadIdx.x;
  if (b < 3680) {
    int i = b * 256 + t;
    const float* s; ushort_t* d; int base;
    if (i < 8192)         { s = w_in;  d = win_bf;  base = 0; }
    else if (i < 24576)   { s = w_lat; d = wlat_bf; base = 8192; }
    else if (i < 40960)   { s = w_b1;  d = wb1_bf;  base = 24576; }
    else if (i < 57344)   { s = w_r1;  d = wr1_bf;  base = 40960; }
    else                  { s = Wp1;   d = wp1_bf;  base = 57344; }
    int j = i - base;
    float4 v = ((const float4*)s)[j];
    short4_t o;
    o[0] = (short)f2bf(v.x); o[1] = (short)f2bf(v.y);
    o[2] = (short)f2bf(v.z); o[3] = (short)f2bf(v.w);
    *(short4_t*)(d + j * 4) = o;
  } else if (b < 3936) {
    int i = (b - 3680) * 256 + t;     // < 512*128
    int k = i >> 7, c = i & 127;
    int u = k >> 7, ci = k & 127;
    const float* wp = w_tf + ((size_t)(c * 128 + ci)) * 3;
    float w0 = wp[0], w1 = wp[1], w2 = wp[2];
    float coef = (u == 0) ? (w0 + w1) : (u == 3) ? (w1 + w2) : (w0 + w1 + w2);
    tct[(size_t)k * 128 + c] = f2bf(0.25f * coef);
  } else if (b < 4192) {
    // wsm reorder: block per n; stage 2304 contiguous floats, write coalesced
    int n = b - 3936;
    float* l2 = &ldsF[0][0];
    const float* src = w_sm + (size_t)n * KP;
    for (int idx = t; idx < 576; idx += 256) {
      float4 v = ((const float4*)src)[idx];
      l2[idx * 4 + 0] = v.x; l2[idx * 4 + 1] = v.y;
      l2[idx * 4 + 2] = v.z; l2[idx * 4 + 3] = v.w;
    }
    __syncthreads();
    ushort_t* dst = wsm_bf + (size_t)n * KP;
#pragma unroll
    for (int tp = 0; tp < 9; ++tp)
      dst[tp * 256 + t] = f2bf(l2[t * 9 + tp]);
  } else if (b < 4204) {
    int i = (b - 4192) * 256 + t;     // < 3072
    if (i < 1536) {
      int l = i >> 8, d = i & 255;
      float a = 0.f;
      for (int o = 0; o < 256; ++o)
        a += bq[l * 256 + o] * Wp2[((size_t)(l * 256 + o)) * 256 + d];
      bqt[i] = a;
    } else {
      int j = i - 1536;
      int l = j >> 8, o2 = j & 255;
      float a = bo[l * 256 + o2];
      for (int o = 0; o < 256; ++o)
        a += bp2[l * 256 + o] * Wo[((size_t)(l * 256 + o2)) * 256 + o];
      bfuse[j] = a;
    }
  } else if (b < 5293) {
    int j = (b - 4204) * 256 + t;
    if (j < 278784) x2p_zero[j] = make_uint4(0u, 0u, 0u, 0u);
  } else if (b < 5294) {
    int d = t;
    if (d < 128) bt[d] = b_tf[d];
    __syncthreads();
    float a = b_in[d];
    for (int c = 0; c < 128; ++c) a += w_in[d * 128 + c] * bt[c];
    bias_comb[d] = a;
  } else if (b < 5894) {
    int i = (b - 5294) * 256 + t;
    if (i < BB * NQ * DM) {
      int rd = i % (NQ * DM);
      float v = qe[rd] + qp[rd];
      queries[i] = v;
      qbf[i] = f2bf(v);
    }
    if (i < BB * NQ * 4) boxes[i] = pb[i];
  } else {
    // feat (b,u,ci,s) fp32 -> featT (b*HW+s, u*128+ci) bf16
    int idx = b - 5894;            // 0..1023
    int gs = idx & 127;
    int k0 = (idx >> 7) * 64;
    int bb = gs >> 6;
    int s0 = (gs & 63) * 64;
    int kk = t >> 2, sc0 = (t & 3) * 16;
    {
      int k = k0 + kk;
      int u = k >> 7, ci = k & 127;
      const float* src = feat + (((size_t)(bb * 4 + u) * 128 + ci) << 12) + s0 + sc0;
#pragma unroll
      for (int j = 0; j < 4; ++j) {
        float4 v = *(const float4*)(src + j * 4);
        ldsF[kk][sc0 + j * 4 + 0] = v.x;
        ldsF[kk][sc0 + j * 4 + 1] = v.y;
        ldsF[kk][sc0 + j * 4 + 2] = v.z;
        ldsF[kk][sc0 + j * 4 + 3] = v.w;
      }
    }
    __syncthreads();
#pragma unroll
    for (int p = 0; p < 2; ++p) {
      int idx2 = p * 256 + t;
      int s_l = idx2 >> 3, kc = (idx2 & 7) * 8;
      short8 v;
#pragma unroll
      for (int j = 0; j < 8; ++j) v[j] = (short)f2bf(ldsF[kc + j][s_l]);
      *(short8*)(featT + (size_t)(bb * 4096 + s0 + s_l) * 512 + k0 + kc) = v;
    }
  }
}

// ---------------------------------------------------------------------------
// Batched weight-composition GEMM, grid (4,4,12), fp32 inputs with LDS
// transpose staging:
//  z<6 : wqt[l][d][c]    = sum_o Wp2[o,d] Wq[o,c]   (A=Wp2^T, B=Wq^T)
//  z>=6: wfuseT[l][dd][o2]= sum_o Wp2[o,dd] Wo[o2,o] (A=Wp2^T, B=Wo straight)
__global__ __launch_bounds__(256) void k_wcompose(const float* __restrict__ Wp2,
                                                  const float* __restrict__ Wq,
                                                  const float* __restrict__ Wo,
                                                  ushort_t* __restrict__ wqt,
                                                  ushort_t* __restrict__ wfuseT) {
  __shared__ ushort_t As[64 * 36];
  __shared__ ushort_t Bs[64 * 36];
  int z = blockIdx.z, l = z % 6;
  const float* Asrc = Wp2 + (size_t)l * 65536;                 // [o][d]
  const float* Bsrc = ((z < 6) ? Wq : Wo) + (size_t)l * 65536;
  ushort_t* C = ((z < 6) ? wqt : wfuseT) + (size_t)l * 65536;
  bool btr = (z < 6);
  int tid = threadIdx.x;
  int bm = blockIdx.x * 64, bn = blockIdx.y * 64;
  int w = tid >> 6, lane = tid & 63;
  int wm = (w & 1) * 32, wn = (w >> 1) * 32;
  int q = lane >> 4, ml = lane & 15;
  f32x4 acc[2][2] = {};
  int oo = tid >> 3, mg = (tid & 7) * 8;   // transpose-stage map
  int nr = tid >> 2, kg = (tid & 3) * 8;   // straight-stage map
  for (int k0 = 0; k0 < 256; k0 += 32) {
    {
      const float* sp = Asrc + (size_t)(k0 + oo) * 256 + bm + mg;
      float4 f0 = *(const float4*)sp;
      float4 f1 = *(const float4*)(sp + 4);
      ushort_t* dst = As + oo;
      dst[(mg + 0) * 36] = f2bf(f0.x); dst[(mg + 1) * 36] = f2bf(f0.y);
      dst[(mg + 2) * 36] = f2bf(f0.z); dst[(mg + 3) * 36] = f2bf(f0.w);
      dst[(mg + 4) * 36] = f2bf(f1.x); dst[(mg + 5) * 36] = f2bf(f1.y);
      dst[(mg + 6) * 36] = f2bf(f1.z); dst[(mg + 7) * 36] = f2bf(f1.w);
    }
    if (btr) {
      const float* sp = Bsrc + (size_t)(k0 + oo) * 256 + bn + mg;
      float4 f0 = *(const float4*)sp;
      float4 f1 = *(const float4*)(sp + 4);
      ushort_t* dst = Bs + oo;
      dst[(mg + 0) * 36] = f2bf(f0.x); dst[(mg + 1) * 36] = f2bf(f0.y);
      dst[(mg + 2) * 36] = f2bf(f0.z); dst[(mg + 3) * 36] = f2bf(f0.w);
      dst[(mg + 4) * 36] = f2bf(f1.x); dst[(mg + 5) * 36] = f2bf(f1.y);
      dst[(mg + 6) * 36] = f2bf(f1.z); dst[(mg + 7) * 36] = f2bf(f1.w);
    } else {
      const float* sp = Bsrc + (size_t)(bn + nr) * 256 + k0 + kg;
      float4 f0 = *(const float4*)sp;
      float4 f1 = *(const float4*)(sp + 4);
      short8 v;
      v[0] = (short)f2bf(f0.x); v[1] = (short)f2bf(f0.y);
      v[2] = (short)f2bf(f0.z); v[3] = (short)f2bf(f0.w);
      v[4] = (short)f2bf(f1.x); v[5] = (short)f2bf(f1.y);
      v[6] = (short)f2bf(f1.z); v[7] = (short)f2bf(f1.w);
      *(short8*)(Bs + nr * 36 + kg) = v;
    }
    __syncthreads();
    short8 a0 = *(const short8*)(As + (wm + ml) * 36 + q * 8);
    short8 a1 = *(const short8*)(As + (wm + 16 + ml) * 36 + q * 8);
    short8 b0 = *(const short8*)(Bs + (wn + ml) * 36 + q * 8);
    short8 b1 = *(const short8*)(Bs + (wn + 16 + ml) * 36 + q * 8);
    acc[0][0] = __builtin_amdgcn_mfma_f32_16x16x32_bf16(a0, b0, acc[0][0], 0, 0, 0);
    acc[0][1] = __builtin_amdgcn_mfma_f32_16x16x32_bf16(a0, b1, acc[0][1], 0, 0, 0);
    acc[1][0] = __builtin_amdgcn_mfma_f32_16x16x32_bf16(a1, b0, acc[1][0], 0, 0, 0);
    acc[1][1] = __builtin_amdgcn_mfma_f32_16x16x32_bf16(a1, b1, acc[1][1], 0, 0, 0);
    __syncthreads();
  }
#pragma unroll
  for (int i = 0; i < 2; ++i)
#pragma unroll
    for (int j = 0; j < 2; ++j) {
      int cn = bn + wn + j * 16 + ml;
#pragma unroll
      for (int r = 0; r < 4; ++r) {
        int rm = bm + wm + i * 16 + q * 4 + r;
        C[(size_t)rm * 256 + cn] = f2bf(acc[i][j][r]);
      }
    }
}

// ---------------------------------------------------------------------------
// Backbone GEMM: xcl = bf16(featT . Wcomb^T + biasc + pos). BM=32, BN=64,
// BK=64.
__global__ __launch_bounds__(256) void k_feat2(const ushort_t* __restrict__ featT,
                                               const ushort_t* __restrict__ wcomb,
                                               const float* __restrict__ biasc,
                                               ushort_t* __restrict__ xcl) {
  __shared__ ushort_t As[32 * 72];
  __shared__ ushort_t Bs[64 * 72];
  __shared__ float dimt_s[256];
  int tid = threadIdx.x;
  {
    int dd = tid & 127;
    int ii = dd >> 1;
    dimt_s[tid] = powf(10000.0f, (2.0f * (float)(ii >> 1)) / 64.0f);
  }
  int bm = blockIdx.x * 32, bn = blockIdx.y * 64;
  int w = tid >> 6, lane = tid & 63;
  int wm = (w & 1) * 16, wn = (w >> 1) * 32;
  int q = lane >> 4, ml = lane & 15;
  int sra = tid >> 3, sca = (tid & 7) * 8;
  int srb = tid >> 2, scb = (tid & 3) * 16;
  const ushort_t* Ag = featT + (size_t)(bm + sra) * 512 + sca;
  const ushort_t* Wg = wcomb + (size_t)(bn + srb) * 512 + scb;
  f32x4 acc[2] = {};
  short8 av = *(const short8*)Ag;
  short8 wv0 = *(const short8*)Wg;
  short8 wv1 = *(const short8*)(Wg + 8);
  for (int k0 = 0; k0 < 512; k0 += 64) {
    *(short8*)(As + sra * 72 + sca) = av;
    *(short8*)(Bs + srb * 72 + scb) = wv0;
    *(short8*)(Bs + srb * 72 + scb + 8) = wv1;
    __syncthreads();
    if (k0 + 64 < 512) {
      av = *(const short8*)(Ag + k0 + 64);
      wv0 = *(const short8*)(Wg + k0 + 64);
      wv1 = *(const short8*)(Wg + k0 + 72);
    }
#pragma unroll
    for (int h = 0; h < 2; ++h) {
      int kc = h * 32 + q * 8;
      short8 a = *(const short8*)(As + (wm + ml) * 72 + kc);
      short8 b0 = *(const short8*)(Bs + (wn + ml) * 72 + kc);
      short8 b1 = *(const short8*)(Bs + (wn + 16 + ml) * 72 + kc);
      acc[0] = __builtin_amdgcn_mfma_f32_16x16x32_bf16(a, b0, acc[0], 0, 0, 0);
      acc[1] = __builtin_amdgcn_mfma_f32_16x16x32_bf16(a, b1, acc[1], 0, 0, 0);
    }
    __syncthreads();
  }
  const float FKT = 6.28318530717958647692f / 64.000001f;
#pragma unroll
  for (int j = 0; j < 2; ++j) {
    int cn = bn + wn + j * 16 + ml;
    float dimt = dimt_s[cn];
    float bC = biasc[cn];
    bool isx = cn >= 128;
    bool isc = cn & 1;
#pragma unroll
    for (int r = 0; r < 4; ++r) {
      int rm = bm + wm + q * 4 + r;
      int s = rm & 4095;
      int y = s >> 6, x = s & 63;
      float ang = (float)((isx ? x : y) + 1) * FKT / dimt;
      float pos = isc ? cosf(ang) : sinf(ang);
      xcl[(size_t)rm * 256 + cn] = f2bf(acc[j][r] + bC + pos);
    }
  }
}

// ---------------------------------------------------------------------------
// bf16 MFMA GEMM, BM=BN=64, BK=64, prefetched staging. K % 64 == 0.
// OUTMODE: 0 fp32 C (bias+ACT); 1 bf16 padded (B,66,66,256); 6 plain bf16.
template <int ACT, int OUTMODE, int MG>
__global__ __launch_bounds__(256) void k_gemm_bf16(const ushort_t* __restrict__ A,
                                                   const ushort_t* __restrict__ W,
                                                   const float* __restrict__ bias,
                                                   const float* __restrict__ res,
                                                   float* __restrict__ Cf,
                                                   ushort_t* __restrict__ Cb,
                                                   int M, int N, int K) {
  __shared__ ushort_t As[64 * 72];
  __shared__ ushort_t Bs[64 * 72];
  int tid = threadIdx.x;
  int bm = blockIdx.x * 64, bn = blockIdx.y * 64;
  int w = tid >> 6, lane = tid & 63;
  int wm = (w & 1) * 32, wn = (w >> 1) * 32;
  int q = lane >> 4, ml = lane & 15;
  f32x4 acc[2][2] = {};
  int srow = tid >> 2, scol = (tid & 3) * 16;
  int ga = bm + srow;
  if (MG) ga = min(ga, M - 1);
  const ushort_t* Ag = A + (size_t)ga * K + scol;
  const ushort_t* Wg = W + (size_t)(bn + srow) * K + scol;
  short8 av0 = *(const short8*)(Ag);
  short8 av1 = *(const short8*)(Ag + 8);
  short8 wv0 = *(const short8*)(Wg);
  short8 wv1 = *(const short8*)(Wg + 8);
  for (int k0 = 0; k0 < K; k0 += 64) {
    *(short8*)(As + srow * 72 + scol) = av0;
    *(short8*)(As + srow * 72 + scol + 8) = av1;
    *(short8*)(Bs + srow * 72 + scol) = wv0;
    *(short8*)(Bs + srow * 72 + scol + 8) = wv1;
    __syncthreads();
    if (k0 + 64 < K) {
      av0 = *(const short8*)(Ag + k0 + 64);
      av1 = *(const short8*)(Ag + k0 + 72);
      wv0 = *(const short8*)(Wg + k0 + 64);
      wv1 = *(const short8*)(Wg + k0 + 72);
    }
#pragma unroll
    for (int h = 0; h < 2; ++h) {
      int kc = h * 32 + q * 8;
      short8 a0 = *(const short8*)(As + (wm + ml) * 72 + kc);
      short8 a1 = *(const short8*)(As + (wm + 16 + ml) * 72 + kc);
      short8 b0 = *(const short8*)(Bs + (wn + ml) * 72 + kc);
      short8 b1 = *(const short8*)(Bs + (wn + 16 + ml) * 72 + kc);
      acc[0][0] = __builtin_amdgcn_mfma_f32_16x16x32_bf16(a0, b0, acc[0][0], 0, 0, 0);
      acc[0][1] = __builtin_amdgcn_mfma_f32_16x16x32_bf16(a0, b1, acc[0][1], 0, 0, 0);
      acc[1][0] = __builtin_amdgcn_mfma_f32_16x16x32_bf16(a1, b0, acc[1][0], 0, 0, 0);
      acc[1][1] = __builtin_amdgcn_mfma_f32_16x16x32_bf16(a1, b1, acc[1][1], 0, 0, 0);
    }
    __syncthreads();
  }
#pragma unroll
  for (int i = 0; i < 2; ++i) {
#pragma unroll
    for (int j = 0; j < 2; ++j) {
      int cn = bn + wn + j * 16 + ml;
      float bsv = bias ? bias[cn] : 0.f;
#pragma unroll
      for (int r = 0; r < 4; ++r) {
        int rm = bm + wm + i * 16 + q * 4 + r;
        if (MG && rm >= M) continue;
        float v = acc[i][j][r] + bsv;
        if (OUTMODE == 0) {
          if (ACT == 1) v = fmaxf(v, 0.f);
          Cf[(size_t)rm * N + cn] = v;
        } else if (OUTMODE == 1) {
          int b = rm >> 12, rem = rm & 4095;
          int y = rem >> 6, xx = rem & 63;
          Cb[(((size_t)(b * 66 + y + 1)) * 66 + xx + 1) * 256 + cn] = f2bf(v);
        } else if (OUTMODE == 6) {
          Cb[(size_t)rm * N + cn] = f2bf(v);
        }
      }
    }
  }
}

// ---------------------------------------------------------------------------
// Small-M bf16 GEMM, BM=32, BN=64, BK=64 (2x block count of BM=64 for
// latency-bound 600-row launches).
// OUTMODE 4: N=512, weights W|W2 per 256-seg: n<256 relu->Cf, else bf16->Cb.
// OUTMODE 7: N=768, W|W2|W3 per 256-seg: n<256 relu->Cf(hb),
//            256..511 relu->(float*)Cb (h1), 512..767 bf16->(ushort*)res (qt).
template <int OUTMODE>
__global__ __launch_bounds__(256) void k_gemm32(const ushort_t* __restrict__ A,
                                                const ushort_t* __restrict__ W,
                                                const float* __restrict__ bias,
                                                const float* __restrict__ res,
                                                float* __restrict__ Cf,
                                                ushort_t* __restrict__ Cb,
                                                int M, int K,
                                                const ushort_t* __restrict__ W2,
                                                const float* __restrict__ bias2,
                                                const ushort_t* __restrict__ W3,
                                                const float* __restrict__ bias3) {
  __shared__ ushort_t As[32 * 72];
  __shared__ ushort_t Bs[64 * 72];
  int tid = threadIdx.x;
  int bm = blockIdx.x * 32, bn = blockIdx.y * 64;
  int w = tid >> 6, lane = tid & 63;
  int wm = (w & 1) * 16, wn = (w >> 1) * 32;
  int q = lane >> 4, ml = lane & 15;
  int sra = tid >> 3, sca = (tid & 7) * 8;
  int srb = tid >> 2, scb = (tid & 3) * 16;
  int ga = min(bm + sra, M - 1);
  const ushort_t* Ag = A + (size_t)ga * K + sca;
  const ushort_t* Wg;
  if (OUTMODE == 7) {
    int seg = bn >> 8;
    const ushort_t* Wb = (seg == 0) ? W : ((seg == 1) ? W2 : W3);
    Wg = Wb + (size_t)((bn & 255) + srb) * K + scb;
  } else {
    const ushort_t* Wb = (bn < 256) ? W : W2;
    Wg = Wb + (size_t)((bn & 255) + srb) * K + scb;
  }
  f32x4 acc[2] = {};
  short8 av = *(const short8*)(Ag);
  short8 wv0 = *(const short8*)(Wg);
  short8 wv1 = *(const short8*)(Wg + 8);
  for (int k0 = 0; k0 < K; k0 += 64) {
    *(short8*)(As + sra * 72 + sca) = av;
    *(short8*)(Bs + srb * 72 + scb) = wv0;
    *(short8*)(Bs + srb * 72 + scb + 8) = wv1;
    __syncthreads();
    if (k0 + 64 < K) {
      av = *(const short8*)(Ag + k0 + 64);
      wv0 = *(const short8*)(Wg + k0 + 64);
      wv1 = *(const short8*)(Wg + k0 + 72);
    }
#pragma unroll
    for (int h = 0; h < 2; ++h) {
      int kc = h * 32 + q * 8;
      short8 a = *(const short8*)(As + (wm + ml) * 72 + kc);
      short8 b0 = *(const short8*)(Bs + (wn + ml) * 72 + kc);
      short8 b1 = *(const short8*)(Bs + (wn + 16 + ml) * 72 + kc);
      acc[0] = __builtin_amdgcn_mfma_f32_16x16x32_bf16(a, b0, acc[0], 0, 0, 0);
      acc[1] = __builtin_amdgcn_mfma_f32_16x16x32_bf16(a, b1, acc[1], 0, 0, 0);
    }
    __syncthreads();
  }
#pragma unroll
  for (int j = 0; j < 2; ++j) {
    int cn = bn + wn + j * 16 + ml;
    float bsv;
    if (OUTMODE == 7) {
      int seg = cn >> 8;
      bsv = ((seg == 0) ? bias : ((seg == 1) ? bias2 : bias3))[cn & 255];
    } else {
      bsv = ((cn < 256) ? bias : bias2)[cn & 255];
    }
#pragma unroll
    for (int r = 0; r < 4; ++r) {
      int rm = bm + wm + q * 4 + r;
      if (rm >= M) continue;
      float v = acc[j][r] + bsv;
      if (OUTMODE == 4) {
        if (cn < 256) Cf[(size_t)rm * 256 + cn] = fmaxf(v, 0.f);
        else Cb[(size_t)rm * 256 + (cn & 255)] = f2bf(v);
      } else {
        if (cn < 256) Cf[(size_t)rm * 256 + cn] = fmaxf(v, 0.f);
        else if (cn < 512) ((float*)Cb)[(size_t)rm * 256 + (cn & 255)] = fmaxf(v, 0.f);
        else ((ushort_t*)res)[(size_t)rm * 256 + (cn & 255)] = f2bf(v);
      }
    }
  }
}

// ---------------------------------------------------------------------------
// Wp1 split-K phase 1: grid (75,2,3), 512 threads (8 waves, 2x4), BM=64,
// BN=128, BK=64.
__global__ __launch_bounds__(512) void k_wp1_split(const ushort_t* __restrict__ A,
                                                   const ushort_t* __restrict__ W,
                                                   ushort_t* __restrict__ part) {
  __shared__ ushort_t As[64 * 72];
  __shared__ ushort_t Bs[128 * 72];
  int tid = threadIdx.x;
  int bm = blockIdx.x * 64, bn = blockIdx.y * 128;
  int kz = blockIdx.z * 768;
  int w = tid >> 6, lane = tid & 63;
  int wm = (w & 1) * 32, wn = (w >> 1) * 32;   // wn in {0,32,64,96}
  int q = lane >> 4, ml = lane & 15;
  int srA = tid >> 3, scA = (tid & 7) * 8;     // 64 rows x 64K / 512 thr
  int srB = tid >> 2, scB = (tid & 3) * 16;    // 128 rows x 64K / 512 thr
  const ushort_t* Ag = A + (size_t)(bm + srA) * KP + kz + scA;
  const ushort_t* Wg = W + (size_t)(bn + srB) * KP + kz + scB;
  f32x4 acc[2][2] = {};
  short8 av = *(const short8*)(Ag);
  short8 wv0 = *(const short8*)(Wg);
  short8 wv1 = *(const short8*)(Wg + 8);
  for (int k0 = 0; k0 < 768; k0 += 64) {
    *(short8*)(As + srA * 72 + scA) = av;
    *(short8*)(Bs + srB * 72 + scB) = wv0;
    *(short8*)(Bs + srB * 72 + scB + 8) = wv1;
    __syncthreads();
    if (k0 + 64 < 768) {
      av = *(const short8*)(Ag + k0 + 64);
      wv0 = *(const short8*)(Wg + k0 + 64);
      wv1 = *(const short8*)(Wg + k0 + 72);
    }
#pragma unroll
    for (int h = 0; h < 2; ++h) {
      int kc = h * 32 + q * 8;
      short8 a0 = *(const short8*)(As + (wm + ml) * 72 + kc);
      short8 a1 = *(const short8*)(As + (wm + 16 + ml) * 72 + kc);
      short8 b0 = *(const short8*)(Bs + (wn + ml) * 72 + kc);
      short8 b1 = *(const short8*)(Bs + (wn + 16 + ml) * 72 + kc);
      acc[0][0] = __builtin_amdgcn_mfma_f32_16x16x32_bf16(a0, b0, acc[0][0], 0, 0, 0);
      acc[0][1] = __builtin_amdgcn_mfma_f32_16x16x32_bf16(a0, b1, acc[0][1], 0, 0, 0);
      acc[1][0] = __builtin_amdgcn_mfma_f32_16x16x32_bf16(a1, b0, acc[1][0], 0, 0, 0);
      acc[1][1] = __builtin_amdgcn_mfma_f32_16x16x32_bf16(a1, b1, acc[1][1], 0, 0, 0);
    }
    __syncthreads();
  }
  ushort_t* pz = part + (size_t)blockIdx.z * 4800 * 256;
#pragma unroll
  for (int i = 0; i < 2; ++i)
#pragma unroll
    for (int j = 0; j < 2; ++j) {
      int cn = bn + wn + j * 16 + ml;
#pragma unroll
      for (int r = 0; r < 4; ++r) {
        int rm = bm + wm + i * 16 + q * 4 + r;
        pz[(size_t)rm * 256 + cn] = f2bf(acc[i][j][r]);
      }
    }
}

// Wp1 split-K phase 2: pvm = bf16( mean_p relu( sum_z part + bias ) )
__global__ __launch_bounds__(256) void k_wp1_reduce(const ushort_t* __restrict__ part,
                                                    const float* __restrict__ bias,
                                                    ushort_t* __restrict__ pvm) {
  int row = blockIdx.x;   // 600
  int d = threadIdx.x;
  float b = bias[d];
  float s = 0.f;
#pragma unroll
  for (int p = 0; p < 8; ++p) {
    size_t idx = (size_t)(row * 8 + p) * 256 + d;
    float v = bf2f(part[idx]) + bf2f(part[idx + (size_t)4800 * 256]) +
              bf2f(part[idx + (size_t)2 * 4800 * 256]) + b;
    s += fmaxf(v, 0.f);
  }
  pvm[(size_t)row * 256 + d] = f2bf(s * 0.125f);
}

// ---------------------------------------------------------------------------
// 3x3 conv as GEMM, 512 threads (8 waves), BM=32, BN=128, BK=64,
// grid (256,2)=512 blocks (same wave count as (256,4)x4w, half the
// weight-panel re-reads, 2x MFMA per barrier).
__global__ __launch_bounds__(512) void k_conv3(const ushort_t* __restrict__ x2p,
                                               const ushort_t* __restrict__ wsm,
                                               const float* __restrict__ bsm,
                                               ushort_t* __restrict__ fcl) {
  __shared__ ushort_t As[32 * 72];
  __shared__ ushort_t Bs[128 * 72];
  int tid = threadIdx.x;
  int bm = blockIdx.x * 32, bn = blockIdx.y * 128;
  int w = tid >> 6, lane = tid & 63;
  int wm = (w & 1) * 16, wn = (w >> 1) * 32;   // wn in {0,32,64,96}
  int q = lane >> 4, ml = lane & 15;
  int sra = tid >> 4, sca = (tid & 15) * 4;    // 32 rows x 64K / 512 thr (short4)
  int srb = tid >> 2, scb = (tid & 3) * 16;    // 128 rows x 64K / 512 thr
  int sA = bm + sra;
  int b = sA >> 12, rem = sA & 4095;
  size_t pbase = ((size_t)(b * 66 + (rem >> 6)) * 66 + (rem & 63)) * 256;
  const ushort_t* Wg = wsm + (size_t)(bn + srb) * KP + scb;
  auto loadA = [&](int k0) {
    int ka = k0 + sca;
    int t9 = ka >> 8;
    int ky = t9 / 3, kx = t9 - ky * 3;
    return *(const short4_t*)(x2p + pbase + (size_t)(ky * 66 + kx) * 256 + (ka & 255));
  };
  f32x4 acc[2] = {};
  short4_t av = loadA(0);
  short8 wv0 = *(const short8*)(Wg);
  short8 wv1 = *(const short8*)(Wg + 8);
  for (int k0 = 0; k0 < KP; k0 += 64) {
    *(short4_t*)(As + sra * 72 + sca) = av;
    *(short8*)(Bs + srb * 72 + scb) = wv0;
    *(short8*)(Bs + srb * 72 + scb + 8) = wv1;
    __syncthreads();
    if (k0 + 64 < KP) {
      av = loadA(k0 + 64);
      wv0 = *(const short8*)(Wg + k0 + 64);
      wv1 = *(const short8*)(Wg + k0 + 72);
    }
#pragma unroll
    for (int h = 0; h < 2; ++h) {
      int kc = h * 32 + q * 8;
      short8 a = *(const short8*)(As + (wm + ml) * 72 + kc);
      short8 b0 = *(const short8*)(Bs + (wn + ml) * 72 + kc);
      short8 b1 = *(const short8*)(Bs + (wn + 16 + ml) * 72 + kc);
      acc[0] = __builtin_amdgcn_mfma_f32_16x16x32_bf16(a, b0, acc[0], 0, 0, 0);
      acc[1] = __builtin_amdgcn_mfma_f32_16x16x32_bf16(a, b1, acc[1], 0, 0, 0);
    }
    __syncthreads();
  }
#pragma unroll
  for (int j = 0; j < 2; ++j) {
    int cn = bn + wn + j * 16 + ml;
    float bsv = bsm[cn];
#pragma unroll
    for (int r = 0; r < 4; ++r) {
      int rm = bm + wm + q * 4 + r;
      fcl[(size_t)rm * 256 + cn] = f2bf(acc[j][r] + bsv);
    }
  }
}

// ---------------------------------------------------------------------------
// Fused box-update + r2ref + bilinear patch sampling. Block per (b,q,p).
// Gather phase remapped: lane = channel-quad (short4 8B loads), wave-group =
// patch subset (3/2/2/2 of 9 positions) -> 4x bytes/instruction.
__global__ __launch_bounds__(256) void k_sample(const ushort_t* __restrict__ fcl,
                                                const float* __restrict__ h1,
                                                const float* __restrict__ w_r2,
                                                const float* __restrict__ b_r2,
                                                const float* __restrict__ boxesIn,
                                                float* __restrict__ boxesOut,
                                                const float* __restrict__ hb,
                                                const float* __restrict__ w_b2,
                                                const float* __restrict__ b_b2,
                                                ushort_t* __restrict__ flat) {
  __shared__ float pr[8];
  __shared__ float bc2[2];
  __shared__ float nb2[2];
  int blk = blockIdx.x;
  int row = blk >> 3, p = blk & 7;
  int b = row / NQ;
  int tid = threadIdx.x;
  int w = tid >> 6, lane = tid & 63;
  if (hb) {
    float4 hv = *(const float4*)(hb + (size_t)row * 256 + lane * 4);
    float4 wv = *(const float4*)(w_b2 + (size_t)w * 256 + lane * 4);
    float aa = hv.x * wv.x + hv.y * wv.y + hv.z * wv.z + hv.w * wv.w;
#pragma unroll
    for (int s = 32; s > 0; s >>= 1) aa += __shfl_down(aa, s, 64);
    if (lane == 0) {
      aa += b_b2[w];
      float delta = 1.0f / (1.0f + expf(-aa));
      float v = boxesIn[row * 4 + w] + 0.1f * tanhf(delta - 0.5f);
      v = fminf(fmaxf(v, 0.f), 1.f);
      if (w < 2) nb2[w] = v;
      if (p == 0) boxesOut[row * 4 + w] = v;
    }
  } else if (tid < 2) {
    nb2[tid] = boxesIn[row * 4 + tid];
  }
  float h = h1[(size_t)row * 256 + tid];
  float px = h * w_r2[(size_t)(2 * p) * 256 + tid];
  float py = h * w_r2[(size_t)(2 * p + 1) * 256 + tid];
#pragma unroll
  for (int s = 32; s > 0; s >>= 1) {
    px += __shfl_down(px, s, 64);
    py += __shfl_down(py, s, 64);
  }
  if (lane == 0) { pr[w * 2] = px; pr[w * 2 + 1] = py; }
  __syncthreads();
  if (tid == 0) {
    float sx = pr[0] + pr[2] + pr[4] + pr[6] + b_r2[2 * p];
    float sy = pr[1] + pr[3] + pr[5] + pr[7] + b_r2[2 * p + 1];
    float rx = nb2[0] + 0.5f * tanhf(sx);
    float ry = nb2[1] + 0.5f * tanhf(sy);
    bc2[0] = fminf(fmaxf(rx, 0.f), 1.f);
    bc2[1] = fminf(fmaxf(ry, 0.f), 1.f);
  }
  __syncthreads();
  float rx = bc2[0], ry = bc2[1];
  const ushort_t* fb = fcl + (size_t)b * HW * DM;
  ushort_t* op = flat + (size_t)blk * KP;
  int c4 = (tid & 63) * 4;
  int g = tid >> 6;
  int p0 = (g == 0) ? 0 : (1 + 2 * g);   // 0,3,5,7
  int p1 = (g == 0) ? 3 : (3 + 2 * g);   // 3,5,7,9
  for (int p9 = p0; p9 < p1; ++p9) {
    int jy = (p9 >= 6) ? 2 : ((p9 >= 3) ? 1 : 0);
    int jx = p9 - jy * 3;
    float yy = (ry + (float)(jy - 1) * (1.0f / 64.0f)) * 63.0f;
    yy = fminf(fmaxf(yy, 0.f), 63.0f);
    float y0f = floorf(yy);
    float wy = yy - y0f;
    int y0 = (int)y0f;
    int y1 = min(y0 + 1, 63);
    float xx = (rx + (float)(jx - 1) * (1.0f / 64.0f)) * 63.0f;
    xx = fminf(fmaxf(xx, 0.f), 63.0f);
    float x0f = floorf(xx);
    float wx = xx - x0f;
    int x0 = (int)x0f;
    int x1 = min(x0 + 1, 63);
    short4_t v00 = *(const short4_t*)(fb + (y0 * 64 + x0) * DM + c4);
    short4_t v01 = *(const short4_t*)(fb + (y0 * 64 + x1) * DM + c4);
    short4_t v10 = *(const short4_t*)(fb + (y1 * 64 + x0) * DM + c4);
    short4_t v11 = *(const short4_t*)(fb + (y1 * 64 + x1) * DM + c4);
    short4_t ov;
#pragma unroll
    for (int jj = 0; jj < 4; ++jj) {
      float v = bf2f((ushort_t)v00[jj]) * (1.f - wx) * (1.f - wy) +
                bf2f((ushort_t)v01[jj]) * wx * (1.f - wy) +
                bf2f((ushort_t)v10[jj]) * (1.f - wx) * wy +
                bf2f((ushort_t)v11[jj]) * wx * wy;
      ov[jj] = (short)f2bf(v);
    }
    *(short4_t*)(op + p9 * DM + c4) = ov;
  }
}

// ---------------------------------------------------------------------------
// Attention in the Wp2-commuted basis, with the ctx@Wfuse update FUSED.
// Softmax reductions via wave shuffle + 4-partial LDS combine (3 barriers
// instead of ~18 tree barriers); raw scores never hit LDS.
__global__ __launch_bounds__(256) void k_attn(const ushort_t* __restrict__ qt,
                                              const ushort_t* __restrict__ pvm,
                                              const ushort_t* __restrict__ wfT,
                                              const float* __restrict__ bfuse_l,
                                              float* __restrict__ queries,
                                              ushort_t* __restrict__ qbf) {
  __shared__ float qs[256];
  __shared__ float sc[512];
  __shared__ float red[8];
  __shared__ float pr4[1024];
  int row = blockIdx.x;
  int b = row / NQ;
  int tid = threadIdx.x;
  int w = tid >> 6, lane = tid & 63;
  qs[tid] = bf2f(qt[(size_t)row * DM + tid]);
  __syncthreads();
  const ushort_t* kvB = pvm + (size_t)b * NQ * DM;
  // scores kept in registers: k=tid (always < NQ) and k=tid+256 (if < NQ)
  float v0, v1 = -1e30f;
  {
    const ushort_t* kp = kvB + (size_t)tid * DM;
    float a = 0.f;
#pragma unroll
    for (int d = 0; d < 256; d += 8) {
      short8 k8 = *(const short8*)(kp + d);
      const float* qd = qs + d;
      a += bf2f((ushort_t)k8[0]) * qd[0];
      a += bf2f((ushort_t)k8[1]) * qd[1];
      a += bf2f((ushort_t)k8[2]) * qd[2];
      a += bf2f((ushort_t)k8[3]) * qd[3];
      a += bf2f((ushort_t)k8[4]) * qd[4];
      a += bf2f((ushort_t)k8[5]) * qd[5];
      a += bf2f((ushort_t)k8[6]) * qd[6];
      a += bf2f((ushort_t)k8[7]) * qd[7];
    }
    v0 = a * (1.0f / 16.0f);
  }
  if (tid + 256 < NQ) {
    const ushort_t* kp = kvB + (size_t)(tid + 256) * DM;
    float a = 0.f;
#pragma unroll
    for (int d = 0; d < 256; d += 8) {
      short8 k8 = *(const short8*)(kp + d);
      const float* qd = qs + d;
      a += bf2f((ushort_t)k8[0]) * qd[0];
      a += bf2f((ushort_t)k8[1]) * qd[1];
      a += bf2f((ushort_t)k8[2]) * qd[2];
      a += bf2f((ushort_t)k8[3]) * qd[3];
      a += bf2f((ushort_t)k8[4]) * qd[4];
      a += bf2f((ushort_t)k8[5]) * qd[5];
      a += bf2f((ushort_t)k8[6]) * qd[6];
      a += bf2f((ushort_t)k8[7]) * qd[7];
    }
    v1 = a * (1.0f / 16.0f);
  }
  // wave-level max reduce + 4-partial combine
  float m = fmaxf(v0, v1);
#pragma unroll
  for (int s = 32; s > 0; s >>= 1) m = fmaxf(m, __shfl_xor(m, s, 64));
  if (lane == 0) red[w] = m;
  __syncthreads();
  float mx = fmaxf(fmaxf(red[0], red[1]), fmaxf(red[2], red[3]));
  float e0 = expf(v0 - mx);
  float e1 = (tid + 256 < NQ) ? expf(v1 - mx) : 0.f;
  sc[tid] = e0;
  sc[tid + 256] = e1;
  float s = e0 + e1;
#pragma unroll
  for (int st = 32; st > 0; st >>= 1) s += __shfl_xor(s, st, 64);
  if (lane == 0) red[4 + w] = s;
  __syncthreads();   // covers sc[] writes + red[4..7]
  float inv = 1.0f / (red[4] + red[5] + red[6] + red[7]);
  float acc = 0.f;
#pragma unroll 4
  for (int k = 0; k < NQ; ++k)
    acc += sc[k] * bf2f(kvB[(size_t)k * DM + tid]);
  // ctx stays in LDS (fp32), fused output projection follows.
  qs[tid] = acc * inv;
  __syncthreads();
  int oq = (tid & 63) * 4, dq = (tid >> 6) * 64;
  float a0 = 0.f, a1 = 0.f, a2 = 0.f, a3 = 0.f;
  const ushort_t* wp = wfT + (size_t)dq * 256 + oq;
#pragma unroll 8
  for (int dd = 0; dd < 64; ++dd) {
    float cc = qs[dq + dd];
    short4_t wv = *(const short4_t*)(wp + (size_t)dd * 256);
    a0 += cc * bf2f((ushort_t)wv[0]);
    a1 += cc * bf2f((ushort_t)wv[1]);
    a2 += cc * bf2f((ushort_t)wv[2]);
    a3 += cc * bf2f((ushort_t)wv[3]);
  }
  float* pb4 = pr4 + (tid >> 6) * 256 + oq;
  pb4[0] = a0; pb4[1] = a1; pb4[2] = a2; pb4[3] = a3;
  __syncthreads();
  float v = pr4[tid] + pr4[256 + tid] + pr4[512 + tid] + pr4[768 + tid] +
            bfuse_l[tid] + queries[(size_t)row * DM + tid];
  queries[(size_t)row * DM + tid] = v;
  qbf[(size_t)row * DM + tid] = f2bf(v);
}

// ---------------------------------------------------------------------------
// Final box update + fused final-output (launched ONCE, after the loop).
__global__ __launch_bounds__(256) void k_boxf(const float* __restrict__ hb,
                                              const float* __restrict__ w_b2,
                                              const float* __restrict__ b_b2,
                                              float* __restrict__ boxes,
                                              int last,
                                              const float* __restrict__ queries,
                                              const float* __restrict__ w_cls,
                                              const float* __restrict__ b_cls,
                                              float* __restrict__ out) {
  __shared__ float nb[4];
  int row = blockIdx.x;
  int tid = threadIdx.x;
  int j = tid >> 6, lane = tid & 63;
  float4 hv = *(const float4*)(hb + (size_t)row * 256 + lane * 4);
  float4 wv = *(const float4*)(w_b2 + (size_t)j * 256 + lane * 4);
  float aa = hv.x * wv.x + hv.y * wv.y + hv.z * wv.z + hv.w * wv.w;
#pragma unroll
  for (int s = 32; s > 0; s >>= 1) aa += __shfl_down(aa, s, 64);
  if (lane == 0) {
    aa += b_b2[j];
    float delta = 1.0f / (1.0f + expf(-aa));
    float v = boxes[row * 4 + j] + 0.1f * tanhf(delta - 0.5f);
    v = fminf(fmaxf(v, 0.f), 1.f);
    boxes[row * 4 + j] = v;
    nb[j] = v;
  }
  if (last) {
    __syncthreads();
    if (j == 0) {
      float4 qv = *(const float4*)(queries + (size_t)row * 256 + lane * 4);
      float4 cv = *(const float4*)(w_cls + lane * 4);
      float a2 = qv.x * cv.x + qv.y * cv.y + qv.z * cv.z + qv.w * cv.w;
#pragma unroll
      for (int s = 32; s > 0; s >>= 1) a2 += __shfl_down(a2, s, 64);
      if (lane == 0) out[row] = a2 + b_cls[0];
    } else if (j == 1 && lane < 4) {
      out[600 + row * 4 + lane] = nb[lane];
    }
  }
}

// ---------------------------------------------------------------------------
extern "C" void kernel_launch(void* const* d_in, const int* in_sizes, int n_in,
                              void* d_out, int out_size, void* d_ws, size_t ws_size,
                              hipStream_t stream) {
  const float* feat   = (const float*)d_in[0];
  const float* pb     = (const float*)d_in[1];
  const float* w_tf   = (const float*)d_in[2];
  const float* b_tf   = (const float*)d_in[3];
  const float* w_in   = (const float*)d_in[4];
  const float* b_in   = (const float*)d_in[5];
  const float* w_lat  = (const float*)d_in[6];
  const float* b_lat  = (const float*)d_in[7];
  const float* w_sm   = (const float*)d_in[8];
  const float* b_sm   = (const float*)d_in[9];
  const float* q_embed= (const float*)d_in[10];
  const float* q_pos  = (const float*)d_in[11];
  const float* Wq     = (const float*)d_in[12];
  const float* bq     = (const float*)d_in[13];
  const float* Wo     = (const float*)d_in[14];
  const float* bo     = (const float*)d_in[15];
  const float* Wp1    = (const float*)d_in[16];
  const float* bp1    = (const float*)d_in[17];
  const float* Wp2    = (const float*)d_in[18];
  const float* bp2    = (const float*)d_in[19];
  const float* w_r1   = (const float*)d_in[20];
  const float* b_r1   = (const float*)d_in[21];
  const float* w_r2   = (const float*)d_in[22];
  const float* b_r2   = (const float*)d_in[23];
  const float* w_b1   = (const float*)d_in[24];
  const float* b_b1   = (const float*)d_in[25];
  const float* w_b2   = (const float*)d_in[26];
  const float* b_b2   = (const float*)d_in[27];
  const float* w_cls  = (const float*)d_in[28];
  const float* b_cls  = (const float*)d_in[29];
  float* out = (float*)d_out;

  float* ws = (float*)d_ws;
  size_t off = 0;
  auto alloc = [&](size_t n) { float* p = ws + off; off += n; return p; };
  ushort_t* flat    = (ushort_t*)alloc(5529600);   // 4800 x 2304 bf16
  ushort_t* part    = (ushort_t*)alloc(1843200);   // 3 x 4800 x 256 bf16
  ushort_t* featT   = (ushort_t*)alloc(2097152);   // 8192 x 512 bf16
  ushort_t* xcl     = (ushort_t*)alloc(1048576);   // 8192 x 256 bf16
  ushort_t* x2p     = (ushort_t*)alloc(1115136);   // 2 x 66 x 66 x 256 bf16
  ushort_t* fcl     = (ushort_t*)alloc(1048576);   // 8192 x 256 bf16
  ushort_t* wcomb   = (ushort_t*)alloc(65536);     // 256 x 512 bf16
  ushort_t* tct     = (ushort_t*)alloc(32768);     // 512 x 128 bf16
  ushort_t* win_bf  = (ushort_t*)alloc(16384);     // 256 x 128 bf16
  float*    biasc   = alloc(256);
  ushort_t* wlat_bf = (ushort_t*)alloc(32768);
  ushort_t* wsm_bf  = (ushort_t*)alloc(294912);
  ushort_t* wp1_bf  = (ushort_t*)alloc(1769472);   // 6 x 256 x 2304
  ushort_t* wb1_bf  = (ushort_t*)alloc(32768);
  ushort_t* wr1_bf  = (ushort_t*)alloc(32768);
  ushort_t* wqt_bf  = (ushort_t*)alloc(196608);    // composed Wqt
  ushort_t* wfuseT  = (ushort_t*)alloc(196608);    // composed (Wo@Wp2)^T
  float*    bqt     = alloc(1536);                 // 6 x 256
  float*    bfuse   = alloc(1536);                 // 6 x 256
  float* queries = alloc(153600);
  ushort_t* qbf  = (ushort_t*)alloc(76800);
  float* h1      = alloc(153600);
  ushort_t* qt   = (ushort_t*)alloc(76800);        // bf16 qt for attention
  float* hb      = alloc(153600);
  ushort_t* pvm  = (ushort_t*)alloc(76800);
  float* boxesA  = alloc(2400);
  float* boxesB  = alloc(2400);
  (void)ws_size; (void)in_sizes; (void)n_in; (void)out_size;

  // --- prep (includes featT transpose) ---
  k_prep<<<6918, 256, 0, stream>>>(w_in, w_lat, w_b1, w_r1, Wp1,
                                   win_bf, wlat_bf, wb1_bf, wr1_bf, wp1_bf,
                                   w_tf, tct, w_sm, wsm_bf,
                                   Wp2, Wo, bq, bp2, bo, bqt, bfuse,
                                   (uint4*)x2p, b_tf, b_in, biasc,
                                   q_embed, q_pos, pb, queries, qbf, boxesA,
                                   feat, featT);
  k_gemm_bf16<0, 6, 0><<<dim3(4, 8), 256, 0, stream>>>(win_bf, tct, nullptr, nullptr,
                                                       nullptr, wcomb, 256, 512, 128);
  k_wcompose<<<dim3(4, 4, 12), 256, 0, stream>>>(Wp2, Wq, Wo, wqt_bf, wfuseT);

  // --- backbone ---
  k_feat2<<<dim3(256, 4), 256, 0, stream>>>(featT, wcomb, biasc, xcl);
  k_gemm_bf16<0, 1, 0><<<dim3(128, 4), 256, 0, stream>>>(xcl, wlat_bf, b_lat, nullptr,
                                                         nullptr, x2p, BB * HW, 256, 256);
  k_conv3<<<dim3(256, 2), 512, 0, stream>>>(x2p, wsm_bf, b_sm, fcl);

  const int M6 = BB * NQ;                 // 600
  const int Mp = BB * NQ * NP;            // 4800
  dim3 g600w((M6 + 31) / 32, 8);          // (19,8)  BM=32
  dim3 g600m((M6 + 31) / 32, 12);         // (19,12) BM=32 merged N=768
  dim3 gsk(Mp / 64, 2, 3);                // (75,2,3) split-K BM=64 BN=128

  // layer-0: h1 = relu(q@w_r1+b_r1) | qt = bf16(q@Wqt[0]+bqt[0])
  k_gemm32<4><<<g600w, 256, 0, stream>>>(qbf, wr1_bf, b_r1, nullptr, h1,
                                         qt, M6, 256,
                                         wqt_bf, bqt, nullptr, nullptr);
  float* bcur = boxesA;
  float* bnext = boxesB;
  for (int l = 0; l < NL; ++l) {
    // fused box-update (l>0) + ref-point + sampling -> flat
    const float* hbp = (l == 0) ? nullptr : hb;
    k_sample<<<Mp, 256, 0, stream>>>(fcl, h1, w_r2, b_r2, bcur, bnext,
                                     hbp, w_b2, b_b2, flat);
    if (l > 0) { float* tmp = bcur; bcur = bnext; bnext = tmp; }
    // Wp1: split-K x3 (bf16 partials) + reduce(relu+pmean) -> pvm
    k_wp1_split<<<gsk, 512, 0, stream>>>(flat, wp1_bf + (size_t)l * 256 * KP, part);
    k_wp1_reduce<<<600, 256, 0, stream>>>(part, bp1 + (size_t)l * DM, pvm);
    // attention + fused output projection
    k_attn<<<M6, 256, 0, stream>>>(qt, pvm, wfuseT + (size_t)l * 65536,
                                   bfuse + l * 256, queries, qbf);
    // merged: hb=relu(q@w_b1) | h1=relu(q@w_r1) | qt=bf16(q@Wqt[l+1])
    int ln = (l + 1) % NL;
    k_gemm32<7><<<g600m, 256, 0, stream>>>(qbf, wb1_bf, b_b1, (const float*)qt,
                                           hb, (ushort_t*)h1, M6, 256,
                                           wr1_bf, b_r1,
                                           wqt_bf + (size_t)ln * 65536,
                                           bqt + ln * 256);
  }
  // final box update (#6) + logits/boxes output
  k_boxf<<<M6, 256, 0, stream>>>(hb, w_b2, b_b2, bcur, 1,
                                 queries, w_cls, b_cls, out);
}

// Round 12
// 638.342 us; speedup vs baseline: 1.3147x; 1.3147x over previous
//
#include <hip/hip_runtime.h>
#include <hip/hip_bf16.h>
#include <math.h>

// Problem constants
#define BB 2
#define TT 4
#define CIN 128
#define DM 256
#define NQ 300
#define NP 8
#define PS 3
#define NL 6
#define HW 4096   // 64*64
#define KP 2304   // 3*3*256

typedef __attribute__((ext_vector_type(8))) short short8;
typedef __attribute__((ext_vector_type(4))) short short4_t;
typedef __attribute__((ext_vector_type(4))) float f32x4;
typedef unsigned short ushort_t;

static __device__ __forceinline__ ushort_t f2bf(float f) {
  __hip_bfloat16 h = __float2bfloat16(f);
  return *reinterpret_cast<ushort_t*>(&h);
}
static __device__ __forceinline__ float bf2f(ushort_t u) {
  return __uint_as_float(((unsigned)u) << 16);
}

// ---------------------------------------------------------------------------
// ONE mega prep kernel (block-range ladder):
//  [0,3680)       plain fp32->bf16 (w_in|w_lat|w_b1|w_r1|Wp1)
//  [3680,3936)    tct coeffs
//  [3936,4192)    wsm reorder (LDS-staged, coalesced both sides; 1 block/n)
//  [4192,4204)    bqt | bfuse
//  [4204,5293)    zero x2p
//  [5293,5294)    bias_comb
//  [5294,5894)    queries/boxes init
//  [5894,6918)    feat transpose -> featT
__global__ void k_prep(const float* __restrict__ w_in, const float* __restrict__ w_lat,
                       const float* __restrict__ w_b1,
                       const float* __restrict__ w_r1, const float* __restrict__ Wp1,
                       ushort_t* __restrict__ win_bf, ushort_t* __restrict__ wlat_bf,
                       ushort_t* __restrict__ wb1_bf,
                       ushort_t* __restrict__ wr1_bf, ushort_t* __restrict__ wp1_bf,
                       const float* __restrict__ w_tf, ushort_t* __restrict__ tct,
                       const float* __restrict__ w_sm, ushort_t* __restrict__ wsm_bf,
                       const float* __restrict__ Wp2, const float* __restrict__ Wo,
                       const float* __restrict__ bq, const float* __restrict__ bp2,
                       const float* __restrict__ bo,
                       float* __restrict__ bqt, float* __restrict__ bfuse,
                       uint4* __restrict__ x2p_zero,
                       const float* __restrict__ b_tf, const float* __restrict__ b_in,
                       float* __restrict__ bias_comb,
                       const float* __restrict__ qe, const float* __restrict__ qp,
                       const float* __restrict__ pb, float* __restrict__ queries,
                       ushort_t* __restrict__ qbf, float* __restrict__ boxes,
                       const float* __restrict__ feat, ushort_t* __restrict__ featT) {
  __shared__ float ldsF[64][65];
  float* bt = &ldsF[0][0];
  int b = blockIdx.x, t = threadIdx.x;
  if (b < 3680) {
    int i = b * 256 + t;
    const float* s; ushort_t* d; int base;
    if (i < 8192)         { s = w_in;  d = win_bf;  base = 0; }
    else if (i < 24576)   { s = w_lat; d = wlat_bf; base = 8192; }
    else if (i < 40960)   { s = w_b1;  d = wb1_bf;  base = 24576; }
    else if (i < 57344)   { s = w_r1;  d = wr1_bf;  base = 40960; }
    else                  { s = Wp1;   d = wp1_bf;  base = 57344; }
    int j = i - base;
    float4 v = ((const float4*)s)[j];
    short4_t o;
    o[0] = (short)f2bf(v.x); o[1] = (short)f2bf(v.y);
    o[2] = (short)f2bf(v.z); o[3] = (short)f2bf(v.w);
    *(short4_t*)(d + j * 4) = o;
  } else if (b < 3936) {
    int i = (b - 3680) * 256 + t;     // < 512*128
    int k = i >> 7, c = i & 127;
    int u = k >> 7, ci = k & 127;
    const float* wp = w_tf + ((size_t)(c * 128 + ci)) * 3;
    float w0 = wp[0], w1 = wp[1], w2 = wp[2];
    float coef = (u == 0) ? (w0 + w1) : (u == 3) ? (w1 + w2) : (w0 + w1 + w2);
    tct[(size_t)k * 128 + c] = f2bf(0.25f * coef);
  } else if (b < 4192) {
    // wsm reorder: block per n; stage 2304 contiguous floats, write coalesced
    int n = b - 3936;
    float* l2 = &ldsF[0][0];
    const float* src = w_sm + (size_t)n * KP;
    for (int idx = t; idx < 576; idx += 256) {
      float4 v = ((const float4*)src)[idx];
      l2[idx * 4 + 0] = v.x; l2[idx * 4 + 1] = v.y;
      l2[idx * 4 + 2] = v.z; l2[idx * 4 + 3] = v.w;
    }
    __syncthreads();
    ushort_t* dst = wsm_bf + (size_t)n * KP;
#pragma unroll
    for (int tp = 0; tp < 9; ++tp)
      dst[tp * 256 + t] = f2bf(l2[t * 9 + tp]);
  } else if (b < 4204) {
    int i = (b - 4192) * 256 + t;     // < 3072
    if (i < 1536) {
      int l = i >> 8, d = i & 255;
      float a = 0.f;
      for (int o = 0; o < 256; ++o)
        a += bq[l * 256 + o] * Wp2[((size_t)(l * 256 + o)) * 256 + d];
      bqt[i] = a;
    } else {
      int j = i - 1536;
      int l = j >> 8, o2 = j & 255;
      float a = bo[l * 256 + o2];
      for (int o = 0; o < 256; ++o)
        a += bp2[l * 256 + o] * Wo[((size_t)(l * 256 + o2)) * 256 + o];
      bfuse[j] = a;
    }
  } else if (b < 5293) {
    int j = (b - 4204) * 256 + t;
    if (j < 278784) x2p_zero[j] = make_uint4(0u, 0u, 0u, 0u);
  } else if (b < 5294) {
    int d = t;
    if (d < 128) bt[d] = b_tf[d];
    __syncthreads();
    float a = b_in[d];
    for (int c = 0; c < 128; ++c) a += w_in[d * 128 + c] * bt[c];
    bias_comb[d] = a;
  } else if (b < 5894) {
    int i = (b - 5294) * 256 + t;
    if (i < BB * NQ * DM) {
      int rd = i % (NQ * DM);
      float v = qe[rd] + qp[rd];
      queries[i] = v;
      qbf[i] = f2bf(v);
    }
    if (i < BB * NQ * 4) boxes[i] = pb[i];
  } else {
    // feat (b,u,ci,s) fp32 -> featT (b*HW+s, u*128+ci) bf16
    int idx = b - 5894;            // 0..1023
    int gs = idx & 127;
    int k0 = (idx >> 7) * 64;
    int bb = gs >> 6;
    int s0 = (gs & 63) * 64;
    int kk = t >> 2, sc0 = (t & 3) * 16;
    {
      int k = k0 + kk;
      int u = k >> 7, ci = k & 127;
      const float* src = feat + (((size_t)(bb * 4 + u) * 128 + ci) << 12) + s0 + sc0;
#pragma unroll
      for (int j = 0; j < 4; ++j) {
        float4 v = *(const float4*)(src + j * 4);
        ldsF[kk][sc0 + j * 4 + 0] = v.x;
        ldsF[kk][sc0 + j * 4 + 1] = v.y;
        ldsF[kk][sc0 + j * 4 + 2] = v.z;
        ldsF[kk][sc0 + j * 4 + 3] = v.w;
      }
    }
    __syncthreads();
#pragma unroll
    for (int p = 0; p < 2; ++p) {
      int idx2 = p * 256 + t;
      int s_l = idx2 >> 3, kc = (idx2 & 7) * 8;
      short8 v;
#pragma unroll
      for (int j = 0; j < 8; ++j) v[j] = (short)f2bf(ldsF[kc + j][s_l]);
      *(short8*)(featT + (size_t)(bb * 4096 + s0 + s_l) * 512 + k0 + kc) = v;
    }
  }
}

// ---------------------------------------------------------------------------
// Batched weight-composition GEMM, grid (4,4,12), fp32 inputs with LDS
// transpose staging:
//  z<6 : wqt[l][d][c]    = sum_o Wp2[o,d] Wq[o,c]   (A=Wp2^T, B=Wq^T)
//  z>=6: wfuseT[l][dd][o2]= sum_o Wp2[o,dd] Wo[o2,o] (A=Wp2^T, B=Wo straight)
__global__ __launch_bounds__(256) void k_wcompose(const float* __restrict__ Wp2,
                                                  const float* __restrict__ Wq,
                                                  const float* __restrict__ Wo,
                                                  ushort_t* __restrict__ wqt,
                                                  ushort_t* __restrict__ wfuseT) {
  __shared__ ushort_t As[64 * 36];
  __shared__ ushort_t Bs[64 * 36];
  int z = blockIdx.z, l = z % 6;
  const float* Asrc = Wp2 + (size_t)l * 65536;                 // [o][d]
  const float* Bsrc = ((z < 6) ? Wq : Wo) + (size_t)l * 65536;
  ushort_t* C = ((z < 6) ? wqt : wfuseT) + (size_t)l * 65536;
  bool btr = (z < 6);
  int tid = threadIdx.x;
  int bm = blockIdx.x * 64, bn = blockIdx.y * 64;
  int w = tid >> 6, lane = tid & 63;
  int wm = (w & 1) * 32, wn = (w >> 1) * 32;
  int q = lane >> 4, ml = lane & 15;
  f32x4 acc[2][2] = {};
  int oo = tid >> 3, mg = (tid & 7) * 8;   // transpose-stage map
  int nr = tid >> 2, kg = (tid & 3) * 8;   // straight-stage map
  for (int k0 = 0; k0 < 256; k0 += 32) {
    {
      const float* sp = Asrc + (size_t)(k0 + oo) * 256 + bm + mg;
      float4 f0 = *(const float4*)sp;
      float4 f1 = *(const float4*)(sp + 4);
      ushort_t* dst = As + oo;
      dst[(mg + 0) * 36] = f2bf(f0.x); dst[(mg + 1) * 36] = f2bf(f0.y);
      dst[(mg + 2) * 36] = f2bf(f0.z); dst[(mg + 3) * 36] = f2bf(f0.w);
      dst[(mg + 4) * 36] = f2bf(f1.x); dst[(mg + 5) * 36] = f2bf(f1.y);
      dst[(mg + 6) * 36] = f2bf(f1.z); dst[(mg + 7) * 36] = f2bf(f1.w);
    }
    if (btr) {
      const float* sp = Bsrc + (size_t)(k0 + oo) * 256 + bn + mg;
      float4 f0 = *(const float4*)sp;
      float4 f1 = *(const float4*)(sp + 4);
      ushort_t* dst = Bs + oo;
      dst[(mg + 0) * 36] = f2bf(f0.x); dst[(mg + 1) * 36] = f2bf(f0.y);
      dst[(mg + 2) * 36] = f2bf(f0.z); dst[(mg + 3) * 36] = f2bf(f0.w);
      dst[(mg + 4) * 36] = f2bf(f1.x); dst[(mg + 5) * 36] = f2bf(f1.y);
      dst[(mg + 6) * 36] = f2bf(f1.z); dst[(mg + 7) * 36] = f2bf(f1.w);
    } else {
      const float* sp = Bsrc + (size_t)(bn + nr) * 256 + k0 + kg;
      float4 f0 = *(const float4*)sp;
      float4 f1 = *(const float4*)(sp + 4);
      short8 v;
      v[0] = (short)f2bf(f0.x); v[1] = (short)f2bf(f0.y);
      v[2] = (short)f2bf(f0.z); v[3] = (short)f2bf(f0.w);
      v[4] = (short)f2bf(f1.x); v[5] = (short)f2bf(f1.y);
      v[6] = (short)f2bf(f1.z); v[7] = (short)f2bf(f1.w);
      *(short8*)(Bs + nr * 36 + kg) = v;
    }
    __syncthreads();
    short8 a0 = *(const short8*)(As + (wm + ml) * 36 + q * 8);
    short8 a1 = *(const short8*)(As + (wm + 16 + ml) * 36 + q * 8);
    short8 b0 = *(const short8*)(Bs + (wn + ml) * 36 + q * 8);
    short8 b1 = *(const short8*)(Bs + (wn + 16 + ml) * 36 + q * 8);
    acc[0][0] = __builtin_amdgcn_mfma_f32_16x16x32_bf16(a0, b0, acc[0][0], 0, 0, 0);
    acc[0][1] = __builtin_amdgcn_mfma_f32_16x16x32_bf16(a0, b1, acc[0][1], 0, 0, 0);
    acc[1][0] = __builtin_amdgcn_mfma_f32_16x16x32_bf16(a1, b0, acc[1][0], 0, 0, 0);
    acc[1][1] = __builtin_amdgcn_mfma_f32_16x16x32_bf16(a1, b1, acc[1][1], 0, 0, 0);
    __syncthreads();
  }
#pragma unroll
  for (int i = 0; i < 2; ++i)
#pragma unroll
    for (int j = 0; j < 2; ++j) {
      int cn = bn + wn + j * 16 + ml;
#pragma unroll
      for (int r = 0; r < 4; ++r) {
        int rm = bm + wm + i * 16 + q * 4 + r;
        C[(size_t)rm * 256 + cn] = f2bf(acc[i][j][r]);
      }
    }
}

// ---------------------------------------------------------------------------
// Backbone GEMM: xcl = bf16(featT . Wcomb^T + biasc + pos). BM=32, BN=64,
// BK=64.
__global__ __launch_bounds__(256) void k_feat2(const ushort_t* __restrict__ featT,
                                               const ushort_t* __restrict__ wcomb,
                                               const float* __restrict__ biasc,
                                               ushort_t* __restrict__ xcl) {
  __shared__ ushort_t As[32 * 72];
  __shared__ ushort_t Bs[64 * 72];
  __shared__ float dimt_s[256];
  int tid = threadIdx.x;
  {
    int dd = tid & 127;
    int ii = dd >> 1;
    dimt_s[tid] = powf(10000.0f, (2.0f * (float)(ii >> 1)) / 64.0f);
  }
  int bm = blockIdx.x * 32, bn = blockIdx.y * 64;
  int w = tid >> 6, lane = tid & 63;
  int wm = (w & 1) * 16, wn = (w >> 1) * 32;
  int q = lane >> 4, ml = lane & 15;
  int sra = tid >> 3, sca = (tid & 7) * 8;
  int srb = tid >> 2, scb = (tid & 3) * 16;
  const ushort_t* Ag = featT + (size_t)(bm + sra) * 512 + sca;
  const ushort_t* Wg = wcomb + (size_t)(bn + srb) * 512 + scb;
  f32x4 acc[2] = {};
  short8 av = *(const short8*)Ag;
  short8 wv0 = *(const short8*)Wg;
  short8 wv1 = *(const short8*)(Wg + 8);
  for (int k0 = 0; k0 < 512; k0 += 64) {
    *(short8*)(As + sra * 72 + sca) = av;
    *(short8*)(Bs + srb * 72 + scb) = wv0;
    *(short8*)(Bs + srb * 72 + scb + 8) = wv1;
    __syncthreads();
    if (k0 + 64 < 512) {
      av = *(const short8*)(Ag + k0 + 64);
      wv0 = *(const short8*)(Wg + k0 + 64);
      wv1 = *(const short8*)(Wg + k0 + 72);
    }
#pragma unroll
    for (int h = 0; h < 2; ++h) {
      int kc = h * 32 + q * 8;
      short8 a = *(const short8*)(As + (wm + ml) * 72 + kc);
      short8 b0 = *(const short8*)(Bs + (wn + ml) * 72 + kc);
      short8 b1 = *(const short8*)(Bs + (wn + 16 + ml) * 72 + kc);
      acc[0] = __builtin_amdgcn_mfma_f32_16x16x32_bf16(a, b0, acc[0], 0, 0, 0);
      acc[1] = __builtin_amdgcn_mfma_f32_16x16x32_bf16(a, b1, acc[1], 0, 0, 0);
    }
    __syncthreads();
  }
  const float FKT = 6.28318530717958647692f / 64.000001f;
#pragma unroll
  for (int j = 0; j < 2; ++j) {
    int cn = bn + wn + j * 16 + ml;
    float dimt = dimt_s[cn];
    float bC = biasc[cn];
    bool isx = cn >= 128;
    bool isc = cn & 1;
#pragma unroll
    for (int r = 0; r < 4; ++r) {
      int rm = bm + wm + q * 4 + r;
      int s = rm & 4095;
      int y = s >> 6, x = s & 63;
      float ang = (float)((isx ? x : y) + 1) * FKT / dimt;
      float pos = isc ? cosf(ang) : sinf(ang);
      xcl[(size_t)rm * 256 + cn] = f2bf(acc[j][r] + bC + pos);
    }
  }
}

// ---------------------------------------------------------------------------
// bf16 MFMA GEMM, BM=BN=64, BK=64, prefetched staging. K % 64 == 0.
// OUTMODE: 0 fp32 C (bias+ACT); 1 bf16 padded (B,66,66,256); 6 plain bf16.
template <int ACT, int OUTMODE, int MG>
__global__ __launch_bounds__(256) void k_gemm_bf16(const ushort_t* __restrict__ A,
                                                   const ushort_t* __restrict__ W,
                                                   const float* __restrict__ bias,
                                                   const float* __restrict__ res,
                                                   float* __restrict__ Cf,
                                                   ushort_t* __restrict__ Cb,
                                                   int M, int N, int K) {
  __shared__ ushort_t As[64 * 72];
  __shared__ ushort_t Bs[64 * 72];
  int tid = threadIdx.x;
  int bm = blockIdx.x * 64, bn = blockIdx.y * 64;
  int w = tid >> 6, lane = tid & 63;
  int wm = (w & 1) * 32, wn = (w >> 1) * 32;
  int q = lane >> 4, ml = lane & 15;
  f32x4 acc[2][2] = {};
  int srow = tid >> 2, scol = (tid & 3) * 16;
  int ga = bm + srow;
  if (MG) ga = min(ga, M - 1);
  const ushort_t* Ag = A + (size_t)ga * K + scol;
  const ushort_t* Wg = W + (size_t)(bn + srow) * K + scol;
  short8 av0 = *(const short8*)(Ag);
  short8 av1 = *(const short8*)(Ag + 8);
  short8 wv0 = *(const short8*)(Wg);
  short8 wv1 = *(const short8*)(Wg + 8);
  for (int k0 = 0; k0 < K; k0 += 64) {
    *(short8*)(As + srow * 72 + scol) = av0;
    *(short8*)(As + srow * 72 + scol + 8) = av1;
    *(short8*)(Bs + srow * 72 + scol) = wv0;
    *(short8*)(Bs + srow * 72 + scol + 8) = wv1;
    __syncthreads();
    if (k0 + 64 < K) {
      av0 = *(const short8*)(Ag + k0 + 64);
      av1 = *(const short8*)(Ag + k0 + 72);
      wv0 = *(const short8*)(Wg + k0 + 64);
      wv1 = *(const short8*)(Wg + k0 + 72);
    }
#pragma unroll
    for (int h = 0; h < 2; ++h) {
      int kc = h * 32 + q * 8;
      short8 a0 = *(const short8*)(As + (wm + ml) * 72 + kc);
      short8 a1 = *(const short8*)(As + (wm + 16 + ml) * 72 + kc);
      short8 b0 = *(const short8*)(Bs + (wn + ml) * 72 + kc);
      short8 b1 = *(const short8*)(Bs + (wn + 16 + ml) * 72 + kc);
      acc[0][0] = __builtin_amdgcn_mfma_f32_16x16x32_bf16(a0, b0, acc[0][0], 0, 0, 0);
      acc[0][1] = __builtin_amdgcn_mfma_f32_16x16x32_bf16(a0, b1, acc[0][1], 0, 0, 0);
      acc[1][0] = __builtin_amdgcn_mfma_f32_16x16x32_bf16(a1, b0, acc[1][0], 0, 0, 0);
      acc[1][1] = __builtin_amdgcn_mfma_f32_16x16x32_bf16(a1, b1, acc[1][1], 0, 0, 0);
    }
    __syncthreads();
  }
#pragma unroll
  for (int i = 0; i < 2; ++i) {
#pragma unroll
    for (int j = 0; j < 2; ++j) {
      int cn = bn + wn + j * 16 + ml;
      float bsv = bias ? bias[cn] : 0.f;
#pragma unroll
      for (int r = 0; r < 4; ++r) {
        int rm = bm + wm + i * 16 + q * 4 + r;
        if (MG && rm >= M) continue;
        float v = acc[i][j][r] + bsv;
        if (OUTMODE == 0) {
          if (ACT == 1) v = fmaxf(v, 0.f);
          Cf[(size_t)rm * N + cn] = v;
        } else if (OUTMODE == 1) {
          int b = rm >> 12, rem = rm & 4095;
          int y = rem >> 6, xx = rem & 63;
          Cb[(((size_t)(b * 66 + y + 1)) * 66 + xx + 1) * 256 + cn] = f2bf(v);
        } else if (OUTMODE == 6) {
          Cb[(size_t)rm * N + cn] = f2bf(v);
        }
      }
    }
  }
}

// ---------------------------------------------------------------------------
// Small-M bf16 GEMM, BM=32, BN=64, BK=64 (2x block count of BM=64 for
// latency-bound 600-row launches).
// OUTMODE 4: N=512, weights W|W2 per 256-seg: n<256 relu->Cf, else bf16->Cb.
// OUTMODE 7: N=768, W|W2|W3 per 256-seg: n<256 relu->Cf(hb),
//            256..511 relu->(float*)Cb (h1), 512..767 bf16->(ushort*)res (qt).
template <int OUTMODE>
__global__ __launch_bounds__(256) void k_gemm32(const ushort_t* __restrict__ A,
                                                const ushort_t* __restrict__ W,
                                                const float* __restrict__ bias,
                                                const float* __restrict__ res,
                                                float* __restrict__ Cf,
                                                ushort_t* __restrict__ Cb,
                                                int M, int K,
                                                const ushort_t* __restrict__ W2,
                                                const float* __restrict__ bias2,
                                                const ushort_t* __restrict__ W3,
                                                const float* __restrict__ bias3) {
  __shared__ ushort_t As[32 * 72];
  __shared__ ushort_t Bs[64 * 72];
  int tid = threadIdx.x;
  int bm = blockIdx.x * 32, bn = blockIdx.y * 64;
  int w = tid >> 6, lane = tid & 63;
  int wm = (w & 1) * 16, wn = (w >> 1) * 32;
  int q = lane >> 4, ml = lane & 15;
  int sra = tid >> 3, sca = (tid & 7) * 8;
  int srb = tid >> 2, scb = (tid & 3) * 16;
  int ga = min(bm + sra, M - 1);
  const ushort_t* Ag = A + (size_t)ga * K + sca;
  const ushort_t* Wg;
  if (OUTMODE == 7) {
    int seg = bn >> 8;
    const ushort_t* Wb = (seg == 0) ? W : ((seg == 1) ? W2 : W3);
    Wg = Wb + (size_t)((bn & 255) + srb) * K + scb;
  } else {
    const ushort_t* Wb = (bn < 256) ? W : W2;
    Wg = Wb + (size_t)((bn & 255) + srb) * K + scb;
  }
  f32x4 acc[2] = {};
  short8 av = *(const short8*)(Ag);
  short8 wv0 = *(const short8*)(Wg);
  short8 wv1 = *(const short8*)(Wg + 8);
  for (int k0 = 0; k0 < K; k0 += 64) {
    *(short8*)(As + sra * 72 + sca) = av;
    *(short8*)(Bs + srb * 72 + scb) = wv0;
    *(short8*)(Bs + srb * 72 + scb + 8) = wv1;
    __syncthreads();
    if (k0 + 64 < K) {
      av = *(const short8*)(Ag + k0 + 64);
      wv0 = *(const short8*)(Wg + k0 + 64);
      wv1 = *(const short8*)(Wg + k0 + 72);
    }
#pragma unroll
    for (int h = 0; h < 2; ++h) {
      int kc = h * 32 + q * 8;
      short8 a = *(const short8*)(As + (wm + ml) * 72 + kc);
      short8 b0 = *(const short8*)(Bs + (wn + ml) * 72 + kc);
      short8 b1 = *(const short8*)(Bs + (wn + 16 + ml) * 72 + kc);
      acc[0] = __builtin_amdgcn_mfma_f32_16x16x32_bf16(a, b0, acc[0], 0, 0, 0);
      acc[1] = __builtin_amdgcn_mfma_f32_16x16x32_bf16(a, b1, acc[1], 0, 0, 0);
    }
    __syncthreads();
  }
#pragma unroll
  for (int j = 0; j < 2; ++j) {
    int cn = bn + wn + j * 16 + ml;
    float bsv;
    if (OUTMODE == 7) {
      int seg = cn >> 8;
      bsv = ((seg == 0) ? bias : ((seg == 1) ? bias2 : bias3))[cn & 255];
    } else {
      bsv = ((cn < 256) ? bias : bias2)[cn & 255];
    }
#pragma unroll
    for (int r = 0; r < 4; ++r) {
      int rm = bm + wm + q * 4 + r;
      if (rm >= M) continue;
      float v = acc[j][r] + bsv;
      if (OUTMODE == 4) {
        if (cn < 256) Cf[(size_t)rm * 256 + cn] = fmaxf(v, 0.f);
        else Cb[(size_t)rm * 256 + (cn & 255)] = f2bf(v);
      } else {
        if (cn < 256) Cf[(size_t)rm * 256 + cn] = fmaxf(v, 0.f);
        else if (cn < 512) ((float*)Cb)[(size_t)rm * 256 + (cn & 255)] = fmaxf(v, 0.f);
        else ((ushort_t*)res)[(size_t)rm * 256 + (cn & 255)] = f2bf(v);
      }
    }
  }
}

// ---------------------------------------------------------------------------
// Wp1 split-K phase 1: grid (75,2,3), 512 threads (8 waves, 2x4), BM=64,
// BN=128, BK=64.
__global__ __launch_bounds__(512) void k_wp1_split(const ushort_t* __restrict__ A,
                                                   const ushort_t* __restrict__ W,
                                                   ushort_t* __restrict__ part) {
  __shared__ ushort_t As[64 * 72];
  __shared__ ushort_t Bs[128 * 72];
  int tid = threadIdx.x;
  int bm = blockIdx.x * 64, bn = blockIdx.y * 128;
  int kz = blockIdx.z * 768;
  int w = tid >> 6, lane = tid & 63;
  int wm = (w & 1) * 32, wn = (w >> 1) * 32;   // wn in {0,32,64,96}
  int q = lane >> 4, ml = lane & 15;
  int srA = tid >> 3, scA = (tid & 7) * 8;     // 64 rows x 64K / 512 thr
  int srB = tid >> 2, scB = (tid & 3) * 16;    // 128 rows x 64K / 512 thr
  const ushort_t* Ag = A + (size_t)(bm + srA) * KP + kz + scA;
  const ushort_t* Wg = W + (size_t)(bn + srB) * KP + kz + scB;
  f32x4 acc[2][2] = {};
  short8 av = *(const short8*)(Ag);
  short8 wv0 = *(const short8*)(Wg);
  short8 wv1 = *(const short8*)(Wg + 8);
  for (int k0 = 0; k0 < 768; k0 += 64) {
    *(short8*)(As + srA * 72 + scA) = av;
    *(short8*)(Bs + srB * 72 + scB) = wv0;
    *(short8*)(Bs + srB * 72 + scB + 8) = wv1;
    __syncthreads();
    if (k0 + 64 < 768) {
      av = *(const short8*)(Ag + k0 + 64);
      wv0 = *(const short8*)(Wg + k0 + 64);
      wv1 = *(const short8*)(Wg + k0 + 72);
    }
#pragma unroll
    for (int h = 0; h < 2; ++h) {
      int kc = h * 32 + q * 8;
      short8 a0 = *(const short8*)(As + (wm + ml) * 72 + kc);
      short8 a1 = *(const short8*)(As + (wm + 16 + ml) * 72 + kc);
      short8 b0 = *(const short8*)(Bs + (wn + ml) * 72 + kc);
      short8 b1 = *(const short8*)(Bs + (wn + 16 + ml) * 72 + kc);
      acc[0][0] = __builtin_amdgcn_mfma_f32_16x16x32_bf16(a0, b0, acc[0][0], 0, 0, 0);
      acc[0][1] = __builtin_amdgcn_mfma_f32_16x16x32_bf16(a0, b1, acc[0][1], 0, 0, 0);
      acc[1][0] = __builtin_amdgcn_mfma_f32_16x16x32_bf16(a1, b0, acc[1][0], 0, 0, 0);
      acc[1][1] = __builtin_amdgcn_mfma_f32_16x16x32_bf16(a1, b1, acc[1][1], 0, 0, 0);
    }
    __syncthreads();
  }
  ushort_t* pz = part + (size_t)blockIdx.z * 4800 * 256;
#pragma unroll
  for (int i = 0; i < 2; ++i)
#pragma unroll
    for (int j = 0; j < 2; ++j) {
      int cn = bn + wn + j * 16 + ml;
#pragma unroll
      for (int r = 0; r < 4; ++r) {
        int rm = bm + wm + i * 16 + q * 4 + r;
        pz[(size_t)rm * 256 + cn] = f2bf(acc[i][j][r]);
      }
    }
}

// Wp1 split-K phase 2: pvm = bf16( mean_p relu( sum_z part + bias ) )
__global__ __launch_bounds__(256) void k_wp1_reduce(const ushort_t* __restrict__ part,
                                                    const float* __restrict__ bias,
                                                    ushort_t* __restrict__ pvm) {
  int row = blockIdx.x;   // 600
  int d = threadIdx.x;
  float b = bias[d];
  float s = 0.f;
#pragma unroll
  for (int p = 0; p < 8; ++p) {
    size_t idx = (size_t)(row * 8 + p) * 256 + d;
    float v = bf2f(part[idx]) + bf2f(part[idx + (size_t)4800 * 256]) +
              bf2f(part[idx + (size_t)2 * 4800 * 256]) + b;
    s += fmaxf(v, 0.f);
  }
  pvm[(size_t)row * 256 + d] = f2bf(s * 0.125f);
}

// ---------------------------------------------------------------------------
// 3x3 conv as GEMM, 512 threads (8 waves), BM=32, BN=128, BK=64,
// grid (256,2)=512 blocks.
__global__ __launch_bounds__(512) void k_conv3(const ushort_t* __restrict__ x2p,
                                               const ushort_t* __restrict__ wsm,
                                               const float* __restrict__ bsm,
                                               ushort_t* __restrict__ fcl) {
  __shared__ ushort_t As[32 * 72];
  __shared__ ushort_t Bs[128 * 72];
  int tid = threadIdx.x;
  int bm = blockIdx.x * 32, bn = blockIdx.y * 128;
  int w = tid >> 6, lane = tid & 63;
  int wm = (w & 1) * 16, wn = (w >> 1) * 32;   // wn in {0,32,64,96}
  int q = lane >> 4, ml = lane & 15;
  int sra = tid >> 4, sca = (tid & 15) * 4;    // 32 rows x 64K / 512 thr (short4)
  int srb = tid >> 2, scb = (tid & 3) * 16;    // 128 rows x 64K / 512 thr
  int sA = bm + sra;
  int b = sA >> 12, rem = sA & 4095;
  size_t pbase = ((size_t)(b * 66 + (rem >> 6)) * 66 + (rem & 63)) * 256;
  const ushort_t* Wg = wsm + (size_t)(bn + srb) * KP + scb;
  auto loadA = [&](int k0) {
    int ka = k0 + sca;
    int t9 = ka >> 8;
    int ky = t9 / 3, kx = t9 - ky * 3;
    return *(const short4_t*)(x2p + pbase + (size_t)(ky * 66 + kx) * 256 + (ka & 255));
  };
  f32x4 acc[2] = {};
  short4_t av = loadA(0);
  short8 wv0 = *(const short8*)(Wg);
  short8 wv1 = *(const short8*)(Wg + 8);
  for (int k0 = 0; k0 < KP; k0 += 64) {
    *(short4_t*)(As + sra * 72 + sca) = av;
    *(short8*)(Bs + srb * 72 + scb) = wv0;
    *(short8*)(Bs + srb * 72 + scb + 8) = wv1;
    __syncthreads();
    if (k0 + 64 < KP) {
      av = loadA(k0 + 64);
      wv0 = *(const short8*)(Wg + k0 + 64);
      wv1 = *(const short8*)(Wg + k0 + 72);
    }
#pragma unroll
    for (int h = 0; h < 2; ++h) {
      int kc = h * 32 + q * 8;
      short8 a = *(const short8*)(As + (wm + ml) * 72 + kc);
      short8 b0 = *(const short8*)(Bs + (wn + ml) * 72 + kc);
      short8 b1 = *(const short8*)(Bs + (wn + 16 + ml) * 72 + kc);
      acc[0] = __builtin_amdgcn_mfma_f32_16x16x32_bf16(a, b0, acc[0], 0, 0, 0);
      acc[1] = __builtin_amdgcn_mfma_f32_16x16x32_bf16(a, b1, acc[1], 0, 0, 0);
    }
    __syncthreads();
  }
#pragma unroll
  for (int j = 0; j < 2; ++j) {
    int cn = bn + wn + j * 16 + ml;
    float bsv = bsm[cn];
#pragma unroll
    for (int r = 0; r < 4; ++r) {
      int rm = bm + wm + q * 4 + r;
      fcl[(size_t)rm * 256 + cn] = f2bf(acc[j][r] + bsv);
    }
  }
}

// ---------------------------------------------------------------------------
// Fused box-update + r2ref + bilinear patch sampling. Block per (b,q,p).
// Gather phase remapped: lane = channel-quad (short4 8B loads), wave-group =
// patch subset (3/2/2/2 of 9 positions) -> 4x bytes/instruction.
__global__ __launch_bounds__(256) void k_sample(const ushort_t* __restrict__ fcl,
                                                const float* __restrict__ h1,
                                                const float* __restrict__ w_r2,
                                                const float* __restrict__ b_r2,
                                                const float* __restrict__ boxesIn,
                                                float* __restrict__ boxesOut,
                                                const float* __restrict__ hb,
                                                const float* __restrict__ w_b2,
                                                const float* __restrict__ b_b2,
                                                ushort_t* __restrict__ flat) {
  __shared__ float pr[8];
  __shared__ float bc2[2];
  __shared__ float nb2[2];
  int blk = blockIdx.x;
  int row = blk >> 3, p = blk & 7;
  int b = row / NQ;
  int tid = threadIdx.x;
  int w = tid >> 6, lane = tid & 63;
  if (hb) {
    float4 hv = *(const float4*)(hb + (size_t)row * 256 + lane * 4);
    float4 wv = *(const float4*)(w_b2 + (size_t)w * 256 + lane * 4);
    float aa = hv.x * wv.x + hv.y * wv.y + hv.z * wv.z + hv.w * wv.w;
#pragma unroll
    for (int s = 32; s > 0; s >>= 1) aa += __shfl_down(aa, s, 64);
    if (lane == 0) {
      aa += b_b2[w];
      float delta = 1.0f / (1.0f + expf(-aa));
      float v = boxesIn[row * 4 + w] + 0.1f * tanhf(delta - 0.5f);
      v = fminf(fmaxf(v, 0.f), 1.f);
      if (w < 2) nb2[w] = v;
      if (p == 0) boxesOut[row * 4 + w] = v;
    }
  } else if (tid < 2) {
    nb2[tid] = boxesIn[row * 4 + tid];
  }
  float h = h1[(size_t)row * 256 + tid];
  float px = h * w_r2[(size_t)(2 * p) * 256 + tid];
  float py = h * w_r2[(size_t)(2 * p + 1) * 256 + tid];
#pragma unroll
  for (int s = 32; s > 0; s >>= 1) {
    px += __shfl_down(px, s, 64);
    py += __shfl_down(py, s, 64);
  }
  if (lane == 0) { pr[w * 2] = px; pr[w * 2 + 1] = py; }
  __syncthreads();
  if (tid == 0) {
    float sx = pr[0] + pr[2] + pr[4] + pr[6] + b_r2[2 * p];
    float sy = pr[1] + pr[3] + pr[5] + pr[7] + b_r2[2 * p + 1];
    float rx = nb2[0] + 0.5f * tanhf(sx);
    float ry = nb2[1] + 0.5f * tanhf(sy);
    bc2[0] = fminf(fmaxf(rx, 0.f), 1.f);
    bc2[1] = fminf(fmaxf(ry, 0.f), 1.f);
  }
  __syncthreads();
  float rx = bc2[0], ry = bc2[1];
  const ushort_t* fb = fcl + (size_t)b * HW * DM;
  ushort_t* op = flat + (size_t)blk * KP;
  int c4 = (tid & 63) * 4;
  int g = tid >> 6;
  int p0 = (g == 0) ? 0 : (1 + 2 * g);   // 0,3,5,7
  int p1 = (g == 0) ? 3 : (3 + 2 * g);   // 3,5,7,9
  for (int p9 = p0; p9 < p1; ++p9) {
    int jy = (p9 >= 6) ? 2 : ((p9 >= 3) ? 1 : 0);
    int jx = p9 - jy * 3;
    float yy = (ry + (float)(jy - 1) * (1.0f / 64.0f)) * 63.0f;
    yy = fminf(fmaxf(yy, 0.f), 63.0f);
    float y0f = floorf(yy);
    float wy = yy - y0f;
    int y0 = (int)y0f;
    int y1 = min(y0 + 1, 63);
    float xx = (rx + (float)(jx - 1) * (1.0f / 64.0f)) * 63.0f;
    xx = fminf(fmaxf(xx, 0.f), 63.0f);
    float x0f = floorf(xx);
    float wx = xx - x0f;
    int x0 = (int)x0f;
    int x1 = min(x0 + 1, 63);
    short4_t v00 = *(const short4_t*)(fb + (y0 * 64 + x0) * DM + c4);
    short4_t v01 = *(const short4_t*)(fb + (y0 * 64 + x1) * DM + c4);
    short4_t v10 = *(const short4_t*)(fb + (y1 * 64 + x0) * DM + c4);
    short4_t v11 = *(const short4_t*)(fb + (y1 * 64 + x1) * DM + c4);
    short4_t ov;
#pragma unroll
    for (int jj = 0; jj < 4; ++jj) {
      float v = bf2f((ushort_t)v00[jj]) * (1.f - wx) * (1.f - wy) +
                bf2f((ushort_t)v01[jj]) * wx * (1.f - wy) +
                bf2f((ushort_t)v10[jj]) * (1.f - wx) * wy +
                bf2f((ushort_t)v11[jj]) * wx * wy;
      ov[jj] = (short)f2bf(v);
    }
    *(short4_t*)(op + p9 * DM + c4) = ov;
  }
}

// ---------------------------------------------------------------------------
// Attention in the Wp2-commuted basis, with the ctx@Wfuse update FUSED.
// (R10-proven form: LDS tree reductions, low VGPR.)
__global__ __launch_bounds__(256) void k_attn(const ushort_t* __restrict__ qt,
                                              const ushort_t* __restrict__ pvm,
                                              const ushort_t* __restrict__ wfT,
                                              const float* __restrict__ bfuse_l,
                                              float* __restrict__ queries,
                                              ushort_t* __restrict__ qbf) {
  __shared__ float qs[256];
  __shared__ float sc[512];
  __shared__ float red[256];
  __shared__ float pr4[1024];
  int row = blockIdx.x;
  int b = row / NQ;
  int tid = threadIdx.x;
  qs[tid] = bf2f(qt[(size_t)row * DM + tid]);
  __syncthreads();
  const ushort_t* kvB = pvm + (size_t)b * NQ * DM;
#pragma unroll
  for (int s2 = 0; s2 < 2; ++s2) {
    int k = tid + s2 * 256;
    float v = -1e30f;
    if (k < NQ) {
      const ushort_t* kp = kvB + (size_t)k * DM;
      float a = 0.f;
#pragma unroll
      for (int d = 0; d < 256; d += 8) {
        short8 k8 = *(const short8*)(kp + d);
        const float* qd = qs + d;
        a += bf2f((ushort_t)k8[0]) * qd[0];
        a += bf2f((ushort_t)k8[1]) * qd[1];
        a += bf2f((ushort_t)k8[2]) * qd[2];
        a += bf2f((ushort_t)k8[3]) * qd[3];
        a += bf2f((ushort_t)k8[4]) * qd[4];
        a += bf2f((ushort_t)k8[5]) * qd[5];
        a += bf2f((ushort_t)k8[6]) * qd[6];
        a += bf2f((ushort_t)k8[7]) * qd[7];
      }
      v = a * (1.0f / 16.0f);
    }
    sc[k] = v;
  }
  __syncthreads();
  red[tid] = fmaxf(sc[tid], sc[tid + 256]);
  __syncthreads();
  for (int st = 128; st > 0; st >>= 1) {
    if (tid < st) red[tid] = fmaxf(red[tid], red[tid + st]);
    __syncthreads();
  }
  float mx = red[0];
  __syncthreads();
  float e0 = (tid < NQ) ? expf(sc[tid] - mx) : 0.f;
  float e1 = (tid + 256 < NQ) ? expf(sc[tid + 256] - mx) : 0.f;
  sc[tid] = e0;
  sc[tid + 256] = e1;
  red[tid] = e0 + e1;
  __syncthreads();
  for (int st = 128; st > 0; st >>= 1) {
    if (tid < st) red[tid] += red[tid + st];
    __syncthreads();
  }
  float inv = 1.0f / red[0];
  __syncthreads();
  float acc = 0.f;
#pragma unroll 4
  for (int k = 0; k < NQ; ++k)
    acc += sc[k] * bf2f(kvB[(size_t)k * DM + tid]);
  // ctx stays in LDS (fp32), fused output projection follows.
  qs[tid] = acc * inv;
  __syncthreads();
  int oq = (tid & 63) * 4, dq = (tid >> 6) * 64;
  float a0 = 0.f, a1 = 0.f, a2 = 0.f, a3 = 0.f;
  const ushort_t* wp = wfT + (size_t)dq * 256 + oq;
#pragma unroll 8
  for (int dd = 0; dd < 64; ++dd) {
    float cc = qs[dq + dd];
    short4_t wv = *(const short4_t*)(wp + (size_t)dd * 256);
    a0 += cc * bf2f((ushort_t)wv[0]);
    a1 += cc * bf2f((ushort_t)wv[1]);
    a2 += cc * bf2f((ushort_t)wv[2]);
    a3 += cc * bf2f((ushort_t)wv[3]);
  }
  float* pb4 = pr4 + (tid >> 6) * 256 + oq;
  pb4[0] = a0; pb4[1] = a1; pb4[2] = a2; pb4[3] = a3;
  __syncthreads();
  float v = pr4[tid] + pr4[256 + tid] + pr4[512 + tid] + pr4[768 + tid] +
            bfuse_l[tid] + queries[(size_t)row * DM + tid];
  queries[(size_t)row * DM + tid] = v;
  qbf[(size_t)row * DM + tid] = f2bf(v);
}

// ---------------------------------------------------------------------------
// Final box update + fused final-output (launched ONCE, after the loop).
__global__ __launch_bounds__(256) void k_boxf(const float* __restrict__ hb,
                                              const float* __restrict__ w_b2,
                                              const float* __restrict__ b_b2,
                                              float* __restrict__ boxes,
                                              int last,
                                              const float* __restrict__ queries,
                                              const float* __restrict__ w_cls,
                                              const float* __restrict__ b_cls,
                                              float* __restrict__ out) {
  __shared__ float nb[4];
  int row = blockIdx.x;
  int tid = threadIdx.x;
  int j = tid >> 6, lane = tid & 63;
  float4 hv = *(const float4*)(hb + (size_t)row * 256 + lane * 4);
  float4 wv = *(const float4*)(w_b2 + (size_t)j * 256 + lane * 4);
  float aa = hv.x * wv.x + hv.y * wv.y + hv.z * wv.z + hv.w * wv.w;
#pragma unroll
  for (int s = 32; s > 0; s >>= 1) aa += __shfl_down(aa, s, 64);
  if (lane == 0) {
    aa += b_b2[j];
    float delta = 1.0f / (1.0f + expf(-aa));
    float v = boxes[row * 4 + j] + 0.1f * tanhf(delta - 0.5f);
    v = fminf(fmaxf(v, 0.f), 1.f);
    boxes[row * 4 + j] = v;
    nb[j] = v;
  }
  if (last) {
    __syncthreads();
    if (j == 0) {
      float4 qv = *(const float4*)(queries + (size_t)row * 256 + lane * 4);
      float4 cv = *(const float4*)(w_cls + lane * 4);
      float a2 = qv.x * cv.x + qv.y * cv.y + qv.z * cv.z + qv.w * cv.w;
#pragma unroll
      for (int s = 32; s > 0; s >>= 1) a2 += __shfl_down(a2, s, 64);
      if (lane == 0) out[row] = a2 + b_cls[0];
    } else if (j == 1 && lane < 4) {
      out[600 + row * 4 + lane] = nb[lane];
    }
  }
}

// ---------------------------------------------------------------------------
extern "C" void kernel_launch(void* const* d_in, const int* in_sizes, int n_in,
                              void* d_out, int out_size, void* d_ws, size_t ws_size,
                              hipStream_t stream) {
  const float* feat   = (const float*)d_in[0];
  const float* pb     = (const float*)d_in[1];
  const float* w_tf   = (const float*)d_in[2];
  const float* b_tf   = (const float*)d_in[3];
  const float* w_in   = (const float*)d_in[4];
  const float* b_in   = (const float*)d_in[5];
  const float* w_lat  = (const float*)d_in[6];
  const float* b_lat  = (const float*)d_in[7];
  const float* w_sm   = (const float*)d_in[8];
  const float* b_sm   = (const float*)d_in[9];
  const float* q_embed= (const float*)d_in[10];
  const float* q_pos  = (const float*)d_in[11];
  const float* Wq     = (const float*)d_in[12];
  const float* bq     = (const float*)d_in[13];
  const float* Wo     = (const float*)d_in[14];
  const float* bo     = (const float*)d_in[15];
  const float* Wp1    = (const float*)d_in[16];
  const float* bp1    = (const float*)d_in[17];
  const float* Wp2    = (const float*)d_in[18];
  const float* bp2    = (const float*)d_in[19];
  const float* w_r1   = (const float*)d_in[20];
  const float* b_r1   = (const float*)d_in[21];
  const float* w_r2   = (const float*)d_in[22];
  const float* b_r2   = (const float*)d_in[23];
  const float* w_b1   = (const float*)d_in[24];
  const float* b_b1   = (const float*)d_in[25];
  const float* w_b2   = (const float*)d_in[26];
  const float* b_b2   = (const float*)d_in[27];
  const float* w_cls  = (const float*)d_in[28];
  const float* b_cls  = (const float*)d_in[29];
  float* out = (float*)d_out;

  float* ws = (float*)d_ws;
  size_t off = 0;
  auto alloc = [&](size_t n) { float* p = ws + off; off += n; return p; };
  ushort_t* flat    = (ushort_t*)alloc(5529600);   // 4800 x 2304 bf16
  ushort_t* part    = (ushort_t*)alloc(1843200);   // 3 x 4800 x 256 bf16
  ushort_t* featT   = (ushort_t*)alloc(2097152);   // 8192 x 512 bf16
  ushort_t* xcl     = (ushort_t*)alloc(1048576);   // 8192 x 256 bf16
  ushort_t* x2p     = (ushort_t*)alloc(1115136);   // 2 x 66 x 66 x 256 bf16
  ushort_t* fcl     = (ushort_t*)alloc(1048576);   // 8192 x 256 bf16
  ushort_t* wcomb   = (ushort_t*)alloc(65536);     // 256 x 512 bf16
  ushort_t* tct     = (ushort_t*)alloc(32768);     // 512 x 128 bf16
  ushort_t* win_bf  = (ushort_t*)alloc(16384);     // 256 x 128 bf16
  float*    biasc   = alloc(256);
  ushort_t* wlat_bf = (ushort_t*)alloc(32768);
  ushort_t* wsm_bf  = (ushort_t*)alloc(294912);
  ushort_t* wp1_bf  = (ushort_t*)alloc(1769472);   // 6 x 256 x 2304
  ushort_t* wb1_bf  = (ushort_t*)alloc(32768);
  ushort_t* wr1_bf  = (ushort_t*)alloc(32768);
  ushort_t* wqt_bf  = (ushort_t*)alloc(196608);    // composed Wqt
  ushort_t* wfuseT  = (ushort_t*)alloc(196608);    // composed (Wo@Wp2)^T
  float*    bqt     = alloc(1536);                 // 6 x 256
  float*    bfuse   = alloc(1536);                 // 6 x 256
  float* queries = alloc(153600);
  ushort_t* qbf  = (ushort_t*)alloc(76800);
  float* h1      = alloc(153600);
  ushort_t* qt   = (ushort_t*)alloc(76800);        // bf16 qt for attention
  float* hb      = alloc(153600);
  ushort_t* pvm  = (ushort_t*)alloc(76800);
  float* boxesA  = alloc(2400);
  float* boxesB  = alloc(2400);
  (void)ws_size; (void)in_sizes; (void)n_in; (void)out_size;

  // --- prep (includes featT transpose) ---
  k_prep<<<6918, 256, 0, stream>>>(w_in, w_lat, w_b1, w_r1, Wp1,
                                   win_bf, wlat_bf, wb1_bf, wr1_bf, wp1_bf,
                                   w_tf, tct, w_sm, wsm_bf,
                                   Wp2, Wo, bq, bp2, bo, bqt, bfuse,
                                   (uint4*)x2p, b_tf, b_in, biasc,
                                   q_embed, q_pos, pb, queries, qbf, boxesA,
                                   feat, featT);
  k_gemm_bf16<0, 6, 0><<<dim3(4, 8), 256, 0, stream>>>(win_bf, tct, nullptr, nullptr,
                                                       nullptr, wcomb, 256, 512, 128);
  k_wcompose<<<dim3(4, 4, 12), 256, 0, stream>>>(Wp2, Wq, Wo, wqt_bf, wfuseT);

  // --- backbone ---
  k_feat2<<<dim3(256, 4), 256, 0, stream>>>(featT, wcomb, biasc, xcl);
  k_gemm_bf16<0, 1, 0><<<dim3(128, 4), 256, 0, stream>>>(xcl, wlat_bf, b_lat, nullptr,
                                                         nullptr, x2p, BB * HW, 256, 256);
  k_conv3<<<dim3(256, 2), 512, 0, stream>>>(x2p, wsm_bf, b_sm, fcl);

  const int M6 = BB * NQ;                 // 600
  const int Mp = BB * NQ * NP;            // 4800
  dim3 g600w((M6 + 31) / 32, 8);          // (19,8)  BM=32
  dim3 g600m((M6 + 31) / 32, 12);         // (19,12) BM=32 merged N=768
  dim3 gsk(Mp / 64, 2, 3);                // (75,2,3) split-K BM=64 BN=128

  // layer-0: h1 = relu(q@w_r1+b_r1) | qt = bf16(q@Wqt[0]+bqt[0])
  k_gemm32<4><<<g600w, 256, 0, stream>>>(qbf, wr1_bf, b_r1, nullptr, h1,
                                         qt, M6, 256,
                                         wqt_bf, bqt, nullptr, nullptr);
  float* bcur = boxesA;
  float* bnext = boxesB;
  for (int l = 0; l < NL; ++l) {
    // fused box-update (l>0) + ref-point + sampling -> flat
    const float* hbp = (l == 0) ? nullptr : hb;
    k_sample<<<Mp, 256, 0, stream>>>(fcl, h1, w_r2, b_r2, bcur, bnext,
                                     hbp, w_b2, b_b2, flat);
    if (l > 0) { float* tmp = bcur; bcur = bnext; bnext = tmp; }
    // Wp1: split-K x3 (bf16 partials) + reduce(relu+pmean) -> pvm
    k_wp1_split<<<gsk, 512, 0, stream>>>(flat, wp1_bf + (size_t)l * 256 * KP, part);
    k_wp1_reduce<<<600, 256, 0, stream>>>(part, bp1 + (size_t)l * DM, pvm);
    // attention + fused output projection
    k_attn<<<M6, 256, 0, stream>>>(qt, pvm, wfuseT + (size_t)l * 65536,
                                   bfuse + l * 256, queries, qbf);
    // merged: hb=relu(q@w_b1) | h1=relu(q@w_r1) | qt=bf16(q@Wqt[l+1])
    int ln = (l + 1) % NL;
    k_gemm32<7><<<g600m, 256, 0, stream>>>(qbf, wb1_bf, b_b1, (const float*)qt,
                                           hb, (ushort_t*)h1, M6, 256,
                                           wr1_bf, b_r1,
                                           wqt_bf + (size_t)ln * 65536,
                                           bqt + ln * 256);
  }
  // final box update (#6) + logits/boxes output
  k_boxf<<<M6, 256, 0, stream>>>(hb, w_b2, b_b2, bcur, 1,
                                 queries, w_cls, b_cls, out);
}

// Round 13
// 633.359 us; speedup vs baseline: 1.3250x; 1.0079x over previous
//
#include <hip/hip_runtime.h>
#include <hip/hip_bf16.h>
#include <math.h>

// Problem constants
#define BB 2
#define TT 4
#define CIN 128
#define DM 256
#define NQ 300
#define NP 8
#define PS 3
#define NL 6
#define HW 4096   // 64*64
#define KP 2304   // 3*3*256

typedef __attribute__((ext_vector_type(8))) short short8;
typedef __attribute__((ext_vector_type(4))) short short4_t;
typedef __attribute__((ext_vector_type(4))) float f32x4;
typedef unsigned short ushort_t;

static __device__ __forceinline__ ushort_t f2bf(float f) {
  __hip_bfloat16 h = __float2bfloat16(f);
  return *reinterpret_cast<ushort_t*>(&h);
}
static __device__ __forceinline__ float bf2f(ushort_t u) {
  return __uint_as_float(((unsigned)u) << 16);
}

// ---------------------------------------------------------------------------
// ONE mega prep kernel (block-range ladder):
//  [0,3680)       plain fp32->bf16 (w_in|w_lat|w_b1|w_r1|Wp1)
//  [3680,3936)    tct coeffs
//  [3936,4192)    wsm reorder (LDS-staged, coalesced both sides; 1 block/n)
//  [4192,4204)    bqt | bfuse
//  [4204,5293)    zero x2p
//  [5293,5294)    bias2[n] = wlat@biasc + b_lat  (biasc recomputed inline)
//  [5294,5422)    Ytab/Xtab: pos@wlat^T separable tables (64 y + 64 x)
//  [5422,6022)    queries/boxes init
//  [6022,7046)    feat transpose -> featT
__global__ void k_prep(const float* __restrict__ w_in, const float* __restrict__ w_lat,
                       const float* __restrict__ w_b1,
                       const float* __restrict__ w_r1, const float* __restrict__ Wp1,
                       ushort_t* __restrict__ win_bf, ushort_t* __restrict__ wlat_bf,
                       ushort_t* __restrict__ wb1_bf,
                       ushort_t* __restrict__ wr1_bf, ushort_t* __restrict__ wp1_bf,
                       const float* __restrict__ w_tf, ushort_t* __restrict__ tct,
                       const float* __restrict__ w_sm, ushort_t* __restrict__ wsm_bf,
                       const float* __restrict__ Wp2, const float* __restrict__ Wo,
                       const float* __restrict__ bq, const float* __restrict__ bp2,
                       const float* __restrict__ bo,
                       float* __restrict__ bqt, float* __restrict__ bfuse,
                       uint4* __restrict__ x2p_zero,
                       const float* __restrict__ b_tf, const float* __restrict__ b_in,
                       const float* __restrict__ b_lat,
                       float* __restrict__ bias2,
                       float* __restrict__ ytab, float* __restrict__ xtab,
                       const float* __restrict__ qe, const float* __restrict__ qp,
                       const float* __restrict__ pb, float* __restrict__ queries,
                       ushort_t* __restrict__ qbf, float* __restrict__ boxes,
                       const float* __restrict__ feat, ushort_t* __restrict__ featT) {
  __shared__ float ldsF[64][65];
  float* bt = &ldsF[0][0];
  int b = blockIdx.x, t = threadIdx.x;
  if (b < 3680) {
    int i = b * 256 + t;
    const float* s; ushort_t* d; int base;
    if (i < 8192)         { s = w_in;  d = win_bf;  base = 0; }
    else if (i < 24576)   { s = w_lat; d = wlat_bf; base = 8192; }
    else if (i < 40960)   { s = w_b1;  d = wb1_bf;  base = 24576; }
    else if (i < 57344)   { s = w_r1;  d = wr1_bf;  base = 40960; }
    else                  { s = Wp1;   d = wp1_bf;  base = 57344; }
    int j = i - base;
    float4 v = ((const float4*)s)[j];
    short4_t o;
    o[0] = (short)f2bf(v.x); o[1] = (short)f2bf(v.y);
    o[2] = (short)f2bf(v.z); o[3] = (short)f2bf(v.w);
    *(short4_t*)(d + j * 4) = o;
  } else if (b < 3936) {
    int i = (b - 3680) * 256 + t;     // < 512*128
    int k = i >> 7, c = i & 127;
    int u = k >> 7, ci = k & 127;
    const float* wp = w_tf + ((size_t)(c * 128 + ci)) * 3;
    float w0 = wp[0], w1 = wp[1], w2 = wp[2];
    float coef = (u == 0) ? (w0 + w1) : (u == 3) ? (w1 + w2) : (w0 + w1 + w2);
    tct[(size_t)k * 128 + c] = f2bf(0.25f * coef);
  } else if (b < 4192) {
    // wsm reorder: block per n; stage 2304 contiguous floats, write coalesced
    int n = b - 3936;
    float* l2 = &ldsF[0][0];
    const float* src = w_sm + (size_t)n * KP;
    for (int idx = t; idx < 576; idx += 256) {
      float4 v = ((const float4*)src)[idx];
      l2[idx * 4 + 0] = v.x; l2[idx * 4 + 1] = v.y;
      l2[idx * 4 + 2] = v.z; l2[idx * 4 + 3] = v.w;
    }
    __syncthreads();
    ushort_t* dst = wsm_bf + (size_t)n * KP;
#pragma unroll
    for (int tp = 0; tp < 9; ++tp)
      dst[tp * 256 + t] = f2bf(l2[t * 9 + tp]);
  } else if (b < 4204) {
    int i = (b - 4192) * 256 + t;     // < 3072
    if (i < 1536) {
      int l = i >> 8, d = i & 255;
      float a = 0.f;
      for (int o = 0; o < 256; ++o)
        a += bq[l * 256 + o] * Wp2[((size_t)(l * 256 + o)) * 256 + d];
      bqt[i] = a;
    } else {
      int j = i - 1536;
      int l = j >> 8, o2 = j & 255;
      float a = bo[l * 256 + o2];
      for (int o = 0; o < 256; ++o)
        a += bp2[l * 256 + o] * Wo[((size_t)(l * 256 + o2)) * 256 + o];
      bfuse[j] = a;
    }
  } else if (b < 5293) {
    int j = (b - 4204) * 256 + t;
    if (j < 278784) x2p_zero[j] = make_uint4(0u, 0u, 0u, 0u);
  } else if (b < 5294) {
    // bias2[n] = sum_c w_lat[n][c]*biasc[c] + b_lat[n],
    // biasc[c] = b_in[c] + sum_cc w_in[c][cc]*b_tf[cc]
    float* btf = &ldsF[0][0];        // 128 floats
    float* bcS = &ldsF[2][0];        // 256 floats (offset 130)
    if (t < 128) btf[t] = b_tf[t];
    __syncthreads();
    float a = b_in[t];
    for (int c = 0; c < 128; ++c) a += w_in[t * 128 + c] * btf[c];
    bcS[t] = a;
    __syncthreads();
    float a2 = b_lat[t];
    for (int c = 0; c < 256; ++c) a2 += w_lat[(size_t)t * 256 + c] * bcS[c];
    bias2[t] = a2;
  } else if (b < 5422) {
    // pos@wlat^T separable tables: idx<64 -> Ytab[y], else Xtab[x]
    int idx = b - 5294;
    int axis = idx >> 6;
    int pos = idx & 63;
    float* v = bt;
    if (t < 128) {
      int c = t;
      float dimt = powf(10000.0f, (2.0f * (float)(c >> 2)) / 64.0f);
      const float FKT = 6.28318530717958647692f / 64.000001f;
      float ang = (float)(pos + 1) * FKT / dimt;
      v[c] = (c & 1) ? cosf(ang) : sinf(ang);
    }
    __syncthreads();
    int off = axis ? 128 : 0;
    float a = 0.f;
    for (int c = 0; c < 128; ++c) a += w_lat[(size_t)t * 256 + off + c] * v[c];
    (axis ? xtab : ytab)[pos * 256 + t] = a;
  } else if (b < 6022) {
    int i = (b - 5422) * 256 + t;
    if (i < BB * NQ * DM) {
      int rd = i % (NQ * DM);
      float v = qe[rd] + qp[rd];
      queries[i] = v;
      qbf[i] = f2bf(v);
    }
    if (i < BB * NQ * 4) boxes[i] = pb[i];
  } else {
    // feat (b,u,ci,s) fp32 -> featT (b*HW+s, u*128+ci) bf16
    int idx = b - 6022;            // 0..1023
    int gs = idx & 127;
    int k0 = (idx >> 7) * 64;
    int bb = gs >> 6;
    int s0 = (gs & 63) * 64;
    int kk = t >> 2, sc0 = (t & 3) * 16;
    {
      int k = k0 + kk;
      int u = k >> 7, ci = k & 127;
      const float* src = feat + (((size_t)(bb * 4 + u) * 128 + ci) << 12) + s0 + sc0;
#pragma unroll
      for (int j = 0; j < 4; ++j) {
        float4 v = *(const float4*)(src + j * 4);
        ldsF[kk][sc0 + j * 4 + 0] = v.x;
        ldsF[kk][sc0 + j * 4 + 1] = v.y;
        ldsF[kk][sc0 + j * 4 + 2] = v.z;
        ldsF[kk][sc0 + j * 4 + 3] = v.w;
      }
    }
    __syncthreads();
#pragma unroll
    for (int p = 0; p < 2; ++p) {
      int idx2 = p * 256 + t;
      int s_l = idx2 >> 3, kc = (idx2 & 7) * 8;
      short8 v;
#pragma unroll
      for (int j = 0; j < 8; ++j) v[j] = (short)f2bf(ldsF[kc + j][s_l]);
      *(short8*)(featT + (size_t)(bb * 4096 + s0 + s_l) * 512 + k0 + kc) = v;
    }
  }
}

// ---------------------------------------------------------------------------
// Batched weight-composition GEMM, grid (4,4,12), fp32 inputs with LDS
// transpose staging:
//  z<6 : wqt[l][d][c]    = sum_o Wp2[o,d] Wq[o,c]   (A=Wp2^T, B=Wq^T)
//  z>=6: wfuseT[l][dd][o2]= sum_o Wp2[o,dd] Wo[o2,o] (A=Wp2^T, B=Wo straight)
__global__ __launch_bounds__(256) void k_wcompose(const float* __restrict__ Wp2,
                                                  const float* __restrict__ Wq,
                                                  const float* __restrict__ Wo,
                                                  ushort_t* __restrict__ wqt,
                                                  ushort_t* __restrict__ wfuseT) {
  __shared__ ushort_t As[64 * 36];
  __shared__ ushort_t Bs[64 * 36];
  int z = blockIdx.z, l = z % 6;
  const float* Asrc = Wp2 + (size_t)l * 65536;                 // [o][d]
  const float* Bsrc = ((z < 6) ? Wq : Wo) + (size_t)l * 65536;
  ushort_t* C = ((z < 6) ? wqt : wfuseT) + (size_t)l * 65536;
  bool btr = (z < 6);
  int tid = threadIdx.x;
  int bm = blockIdx.x * 64, bn = blockIdx.y * 64;
  int w = tid >> 6, lane = tid & 63;
  int wm = (w & 1) * 32, wn = (w >> 1) * 32;
  int q = lane >> 4, ml = lane & 15;
  f32x4 acc[2][2] = {};
  int oo = tid >> 3, mg = (tid & 7) * 8;   // transpose-stage map
  int nr = tid >> 2, kg = (tid & 3) * 8;   // straight-stage map
  for (int k0 = 0; k0 < 256; k0 += 32) {
    {
      const float* sp = Asrc + (size_t)(k0 + oo) * 256 + bm + mg;
      float4 f0 = *(const float4*)sp;
      float4 f1 = *(const float4*)(sp + 4);
      ushort_t* dst = As + oo;
      dst[(mg + 0) * 36] = f2bf(f0.x); dst[(mg + 1) * 36] = f2bf(f0.y);
      dst[(mg + 2) * 36] = f2bf(f0.z); dst[(mg + 3) * 36] = f2bf(f0.w);
      dst[(mg + 4) * 36] = f2bf(f1.x); dst[(mg + 5) * 36] = f2bf(f1.y);
      dst[(mg + 6) * 36] = f2bf(f1.z); dst[(mg + 7) * 36] = f2bf(f1.w);
    }
    if (btr) {
      const float* sp = Bsrc + (size_t)(k0 + oo) * 256 + bn + mg;
      float4 f0 = *(const float4*)sp;
      float4 f1 = *(const float4*)(sp + 4);
      ushort_t* dst = Bs + oo;
      dst[(mg + 0) * 36] = f2bf(f0.x); dst[(mg + 1) * 36] = f2bf(f0.y);
      dst[(mg + 2) * 36] = f2bf(f0.z); dst[(mg + 3) * 36] = f2bf(f0.w);
      dst[(mg + 4) * 36] = f2bf(f1.x); dst[(mg + 5) * 36] = f2bf(f1.y);
      dst[(mg + 6) * 36] = f2bf(f1.z); dst[(mg + 7) * 36] = f2bf(f1.w);
    } else {
      const float* sp = Bsrc + (size_t)(bn + nr) * 256 + k0 + kg;
      float4 f0 = *(const float4*)sp;
      float4 f1 = *(const float4*)(sp + 4);
      short8 v;
      v[0] = (short)f2bf(f0.x); v[1] = (short)f2bf(f0.y);
      v[2] = (short)f2bf(f0.z); v[3] = (short)f2bf(f0.w);
      v[4] = (short)f2bf(f1.x); v[5] = (short)f2bf(f1.y);
      v[6] = (short)f2bf(f1.z); v[7] = (short)f2bf(f1.w);
      *(short8*)(Bs + nr * 36 + kg) = v;
    }
    __syncthreads();
    short8 a0 = *(const short8*)(As + (wm + ml) * 36 + q * 8);
    short8 a1 = *(const short8*)(As + (wm + 16 + ml) * 36 + q * 8);
    short8 b0 = *(const short8*)(Bs + (wn + ml) * 36 + q * 8);
    short8 b1 = *(const short8*)(Bs + (wn + 16 + ml) * 36 + q * 8);
    acc[0][0] = __builtin_amdgcn_mfma_f32_16x16x32_bf16(a0, b0, acc[0][0], 0, 0, 0);
    acc[0][1] = __builtin_amdgcn_mfma_f32_16x16x32_bf16(a0, b1, acc[0][1], 0, 0, 0);
    acc[1][0] = __builtin_amdgcn_mfma_f32_16x16x32_bf16(a1, b0, acc[1][0], 0, 0, 0);
    acc[1][1] = __builtin_amdgcn_mfma_f32_16x16x32_bf16(a1, b1, acc[1][1], 0, 0, 0);
    __syncthreads();
  }
#pragma unroll
  for (int i = 0; i < 2; ++i)
#pragma unroll
    for (int j = 0; j < 2; ++j) {
      int cn = bn + wn + j * 16 + ml;
#pragma unroll
      for (int r = 0; r < 4; ++r) {
        int rm = bm + wm + i * 16 + q * 4 + r;
        C[(size_t)rm * 256 + cn] = f2bf(acc[i][j][r]);
      }
    }
}

// ---------------------------------------------------------------------------
// Backbone GEMM (lateral folded in): x2p = bf16(featT . wcomb2^T + bias2 +
// Ytab[y] + Xtab[x]), written PADDED (B,66,66,256). BM=32, BN=64, BK=64.
__global__ __launch_bounds__(256) void k_feat2(const ushort_t* __restrict__ featT,
                                               const ushort_t* __restrict__ wcomb2,
                                               const float* __restrict__ bias2,
                                               const float* __restrict__ ytab,
                                               const float* __restrict__ xtab,
                                               ushort_t* __restrict__ x2p) {
  __shared__ ushort_t As[32 * 72];
  __shared__ ushort_t Bs[64 * 72];
  int tid = threadIdx.x;
  int bm = blockIdx.x * 32, bn = blockIdx.y * 64;
  int w = tid >> 6, lane = tid & 63;
  int wm = (w & 1) * 16, wn = (w >> 1) * 32;
  int q = lane >> 4, ml = lane & 15;
  int sra = tid >> 3, sca = (tid & 7) * 8;
  int srb = tid >> 2, scb = (tid & 3) * 16;
  const ushort_t* Ag = featT + (size_t)(bm + sra) * 512 + sca;
  const ushort_t* Wg = wcomb2 + (size_t)(bn + srb) * 512 + scb;
  f32x4 acc[2] = {};
  short8 av = *(const short8*)Ag;
  short8 wv0 = *(const short8*)Wg;
  short8 wv1 = *(const short8*)(Wg + 8);
  for (int k0 = 0; k0 < 512; k0 += 64) {
    *(short8*)(As + sra * 72 + sca) = av;
    *(short8*)(Bs + srb * 72 + scb) = wv0;
    *(short8*)(Bs + srb * 72 + scb + 8) = wv1;
    __syncthreads();
    if (k0 + 64 < 512) {
      av = *(const short8*)(Ag + k0 + 64);
      wv0 = *(const short8*)(Wg + k0 + 64);
      wv1 = *(const short8*)(Wg + k0 + 72);
    }
#pragma unroll
    for (int h = 0; h < 2; ++h) {
      int kc = h * 32 + q * 8;
      short8 a = *(const short8*)(As + (wm + ml) * 72 + kc);
      short8 b0 = *(const short8*)(Bs + (wn + ml) * 72 + kc);
      short8 b1 = *(const short8*)(Bs + (wn + 16 + ml) * 72 + kc);
      acc[0] = __builtin_amdgcn_mfma_f32_16x16x32_bf16(a, b0, acc[0], 0, 0, 0);
      acc[1] = __builtin_amdgcn_mfma_f32_16x16x32_bf16(a, b1, acc[1], 0, 0, 0);
    }
    __syncthreads();
  }
#pragma unroll
  for (int j = 0; j < 2; ++j) {
    int cn = bn + wn + j * 16 + ml;
    float bC = bias2[cn];
#pragma unroll
    for (int r = 0; r < 4; ++r) {
      int rm = bm + wm + q * 4 + r;
      int bb2 = rm >> 12, rem = rm & 4095;
      int y = rem >> 6, x = rem & 63;
      float val = acc[j][r] + bC + ytab[y * 256 + cn] + xtab[x * 256 + cn];
      x2p[(((size_t)(bb2 * 66 + y + 1)) * 66 + x + 1) * 256 + cn] = f2bf(val);
    }
  }
}

// ---------------------------------------------------------------------------
// bf16 MFMA GEMM, BM=BN=64, BK=64, prefetched staging. K % 64 == 0.
// OUTMODE: 0 fp32 C (bias+ACT); 6 plain bf16 out; 8 bf16 TRANSPOSED out
// (Cb[cn*256+rm], used for wcombT; M must be 256).
template <int ACT, int OUTMODE, int MG>
__global__ __launch_bounds__(256) void k_gemm_bf16(const ushort_t* __restrict__ A,
                                                   const ushort_t* __restrict__ W,
                                                   const float* __restrict__ bias,
                                                   const float* __restrict__ res,
                                                   float* __restrict__ Cf,
                                                   ushort_t* __restrict__ Cb,
                                                   int M, int N, int K) {
  __shared__ ushort_t As[64 * 72];
  __shared__ ushort_t Bs[64 * 72];
  int tid = threadIdx.x;
  int bm = blockIdx.x * 64, bn = blockIdx.y * 64;
  int w = tid >> 6, lane = tid & 63;
  int wm = (w & 1) * 32, wn = (w >> 1) * 32;
  int q = lane >> 4, ml = lane & 15;
  f32x4 acc[2][2] = {};
  int srow = tid >> 2, scol = (tid & 3) * 16;
  int ga = bm + srow;
  if (MG) ga = min(ga, M - 1);
  const ushort_t* Ag = A + (size_t)ga * K + scol;
  const ushort_t* Wg = W + (size_t)(bn + srow) * K + scol;
  short8 av0 = *(const short8*)(Ag);
  short8 av1 = *(const short8*)(Ag + 8);
  short8 wv0 = *(const short8*)(Wg);
  short8 wv1 = *(const short8*)(Wg + 8);
  for (int k0 = 0; k0 < K; k0 += 64) {
    *(short8*)(As + srow * 72 + scol) = av0;
    *(short8*)(As + srow * 72 + scol + 8) = av1;
    *(short8*)(Bs + srow * 72 + scol) = wv0;
    *(short8*)(Bs + srow * 72 + scol + 8) = wv1;
    __syncthreads();
    if (k0 + 64 < K) {
      av0 = *(const short8*)(Ag + k0 + 64);
      av1 = *(const short8*)(Ag + k0 + 72);
      wv0 = *(const short8*)(Wg + k0 + 64);
      wv1 = *(const short8*)(Wg + k0 + 72);
    }
#pragma unroll
    for (int h = 0; h < 2; ++h) {
      int kc = h * 32 + q * 8;
      short8 a0 = *(const short8*)(As + (wm + ml) * 72 + kc);
      short8 a1 = *(const short8*)(As + (wm + 16 + ml) * 72 + kc);
      short8 b0 = *(const short8*)(Bs + (wn + ml) * 72 + kc);
      short8 b1 = *(const short8*)(Bs + (wn + 16 + ml) * 72 + kc);
      acc[0][0] = __builtin_amdgcn_mfma_f32_16x16x32_bf16(a0, b0, acc[0][0], 0, 0, 0);
      acc[0][1] = __builtin_amdgcn_mfma_f32_16x16x32_bf16(a0, b1, acc[0][1], 0, 0, 0);
      acc[1][0] = __builtin_amdgcn_mfma_f32_16x16x32_bf16(a1, b0, acc[1][0], 0, 0, 0);
      acc[1][1] = __builtin_amdgcn_mfma_f32_16x16x32_bf16(a1, b1, acc[1][1], 0, 0, 0);
    }
    __syncthreads();
  }
#pragma unroll
  for (int i = 0; i < 2; ++i) {
#pragma unroll
    for (int j = 0; j < 2; ++j) {
      int cn = bn + wn + j * 16 + ml;
      float bsv = bias ? bias[cn] : 0.f;
#pragma unroll
      for (int r = 0; r < 4; ++r) {
        int rm = bm + wm + i * 16 + q * 4 + r;
        if (MG && rm >= M) continue;
        float v = acc[i][j][r] + bsv;
        if (OUTMODE == 0) {
          if (ACT == 1) v = fmaxf(v, 0.f);
          Cf[(size_t)rm * N + cn] = v;
        } else if (OUTMODE == 6) {
          Cb[(size_t)rm * N + cn] = f2bf(v);
        } else if (OUTMODE == 8) {
          Cb[(size_t)cn * 256 + rm] = f2bf(v);
        }
      }
    }
  }
}

// ---------------------------------------------------------------------------
// Small-M bf16 GEMM, BM=32, BN=64, BK=64 (2x block count of BM=64 for
// latency-bound 600-row launches).
// OUTMODE 4: N=512, weights W|W2 per 256-seg: n<256 relu->Cf, else bf16->Cb.
// OUTMODE 7: N=768, W|W2|W3 per 256-seg: n<256 relu->Cf(hb),
//            256..511 relu->(float*)Cb (h1), 512..767 bf16->(ushort*)res (qt).
template <int OUTMODE>
__global__ __launch_bounds__(256) void k_gemm32(const ushort_t* __restrict__ A,
                                                const ushort_t* __restrict__ W,
                                                const float* __restrict__ bias,
                                                const float* __restrict__ res,
                                                float* __restrict__ Cf,
                                                ushort_t* __restrict__ Cb,
                                                int M, int K,
                                                const ushort_t* __restrict__ W2,
                                                const float* __restrict__ bias2,
                                                const ushort_t* __restrict__ W3,
                                                const float* __restrict__ bias3) {
  __shared__ ushort_t As[32 * 72];
  __shared__ ushort_t Bs[64 * 72];
  int tid = threadIdx.x;
  int bm = blockIdx.x * 32, bn = blockIdx.y * 64;
  int w = tid >> 6, lane = tid & 63;
  int wm = (w & 1) * 16, wn = (w >> 1) * 32;
  int q = lane >> 4, ml = lane & 15;
  int sra = tid >> 3, sca = (tid & 7) * 8;
  int srb = tid >> 2, scb = (tid & 3) * 16;
  int ga = min(bm + sra, M - 1);
  const ushort_t* Ag = A + (size_t)ga * K + sca;
  const ushort_t* Wg;
  if (OUTMODE == 7) {
    int seg = bn >> 8;
    const ushort_t* Wb = (seg == 0) ? W : ((seg == 1) ? W2 : W3);
    Wg = Wb + (size_t)((bn & 255) + srb) * K + scb;
  } else {
    const ushort_t* Wb = (bn < 256) ? W : W2;
    Wg = Wb + (size_t)((bn & 255) + srb) * K + scb;
  }
  f32x4 acc[2] = {};
  short8 av = *(const short8*)(Ag);
  short8 wv0 = *(const short8*)(Wg);
  short8 wv1 = *(const short8*)(Wg + 8);
  for (int k0 = 0; k0 < K; k0 += 64) {
    *(short8*)(As + sra * 72 + sca) = av;
    *(short8*)(Bs + srb * 72 + scb) = wv0;
    *(short8*)(Bs + srb * 72 + scb + 8) = wv1;
    __syncthreads();
    if (k0 + 64 < K) {
      av = *(const short8*)(Ag + k0 + 64);
      wv0 = *(const short8*)(Wg + k0 + 64);
      wv1 = *(const short8*)(Wg + k0 + 72);
    }
#pragma unroll
    for (int h = 0; h < 2; ++h) {
      int kc = h * 32 + q * 8;
      short8 a = *(const short8*)(As + (wm + ml) * 72 + kc);
      short8 b0 = *(const short8*)(Bs + (wn + ml) * 72 + kc);
      short8 b1 = *(const short8*)(Bs + (wn + 16 + ml) * 72 + kc);
      acc[0] = __builtin_amdgcn_mfma_f32_16x16x32_bf16(a, b0, acc[0], 0, 0, 0);
      acc[1] = __builtin_amdgcn_mfma_f32_16x16x32_bf16(a, b1, acc[1], 0, 0, 0);
    }
    __syncthreads();
  }
#pragma unroll
  for (int j = 0; j < 2; ++j) {
    int cn = bn + wn + j * 16 + ml;
    float bsv;
    if (OUTMODE == 7) {
      int seg = cn >> 8;
      bsv = ((seg == 0) ? bias : ((seg == 1) ? bias2 : bias3))[cn & 255];
    } else {
      bsv = ((cn < 256) ? bias : bias2)[cn & 255];
    }
#pragma unroll
    for (int r = 0; r < 4; ++r) {
      int rm = bm + wm + q * 4 + r;
      if (rm >= M) continue;
      float v = acc[j][r] + bsv;
      if (OUTMODE == 4) {
        if (cn < 256) Cf[(size_t)rm * 256 + cn] = fmaxf(v, 0.f);
        else Cb[(size_t)rm * 256 + (cn & 255)] = f2bf(v);
      } else {
        if (cn < 256) Cf[(size_t)rm * 256 + cn] = fmaxf(v, 0.f);
        else if (cn < 512) ((float*)Cb)[(size_t)rm * 256 + (cn & 255)] = fmaxf(v, 0.f);
        else ((ushort_t*)res)[(size_t)rm * 256 + (cn & 255)] = f2bf(v);
      }
    }
  }
}

// ---------------------------------------------------------------------------
// Wp1 split-K phase 1: grid (75,2,3), 512 threads (8 waves, 2x4), BM=64,
// BN=128, BK=64.
__global__ __launch_bounds__(512) void k_wp1_split(const ushort_t* __restrict__ A,
                                                   const ushort_t* __restrict__ W,
                                                   ushort_t* __restrict__ part) {
  __shared__ ushort_t As[64 * 72];
  __shared__ ushort_t Bs[128 * 72];
  int tid = threadIdx.x;
  int bm = blockIdx.x * 64, bn = blockIdx.y * 128;
  int kz = blockIdx.z * 768;
  int w = tid >> 6, lane = tid & 63;
  int wm = (w & 1) * 32, wn = (w >> 1) * 32;   // wn in {0,32,64,96}
  int q = lane >> 4, ml = lane & 15;
  int srA = tid >> 3, scA = (tid & 7) * 8;     // 64 rows x 64K / 512 thr
  int srB = tid >> 2, scB = (tid & 3) * 16;    // 128 rows x 64K / 512 thr
  const ushort_t* Ag = A + (size_t)(bm + srA) * KP + kz + scA;
  const ushort_t* Wg = W + (size_t)(bn + srB) * KP + kz + scB;
  f32x4 acc[2][2] = {};
  short8 av = *(const short8*)(Ag);
  short8 wv0 = *(const short8*)(Wg);
  short8 wv1 = *(const short8*)(Wg + 8);
  for (int k0 = 0; k0 < 768; k0 += 64) {
    *(short8*)(As + srA * 72 + scA) = av;
    *(short8*)(Bs + srB * 72 + scB) = wv0;
    *(short8*)(Bs + srB * 72 + scB + 8) = wv1;
    __syncthreads();
    if (k0 + 64 < 768) {
      av = *(const short8*)(Ag + k0 + 64);
      wv0 = *(const short8*)(Wg + k0 + 64);
      wv1 = *(const short8*)(Wg + k0 + 72);
    }
#pragma unroll
    for (int h = 0; h < 2; ++h) {
      int kc = h * 32 + q * 8;
      short8 a0 = *(const short8*)(As + (wm + ml) * 72 + kc);
      short8 a1 = *(const short8*)(As + (wm + 16 + ml) * 72 + kc);
      short8 b0 = *(const short8*)(Bs + (wn + ml) * 72 + kc);
      short8 b1 = *(const short8*)(Bs + (wn + 16 + ml) * 72 + kc);
      acc[0][0] = __builtin_amdgcn_mfma_f32_16x16x32_bf16(a0, b0, acc[0][0], 0, 0, 0);
      acc[0][1] = __builtin_amdgcn_mfma_f32_16x16x32_bf16(a0, b1, acc[0][1], 0, 0, 0);
      acc[1][0] = __builtin_amdgcn_mfma_f32_16x16x32_bf16(a1, b0, acc[1][0], 0, 0, 0);
      acc[1][1] = __builtin_amdgcn_mfma_f32_16x16x32_bf16(a1, b1, acc[1][1], 0, 0, 0);
    }
    __syncthreads();
  }
  ushort_t* pz = part + (size_t)blockIdx.z * 4800 * 256;
#pragma unroll
  for (int i = 0; i < 2; ++i)
#pragma unroll
    for (int j = 0; j < 2; ++j) {
      int cn = bn + wn + j * 16 + ml;
#pragma unroll
      for (int r = 0; r < 4; ++r) {
        int rm = bm + wm + i * 16 + q * 4 + r;
        pz[(size_t)rm * 256 + cn] = f2bf(acc[i][j][r]);
      }
    }
}

// Wp1 split-K phase 2: pvm = bf16( mean_p relu( sum_z part + bias ) )
__global__ __launch_bounds__(256) void k_wp1_reduce(const ushort_t* __restrict__ part,
                                                    const float* __restrict__ bias,
                                                    ushort_t* __restrict__ pvm) {
  int row = blockIdx.x;   // 600
  int d = threadIdx.x;
  float b = bias[d];
  float s = 0.f;
#pragma unroll
  for (int p = 0; p < 8; ++p) {
    size_t idx = (size_t)(row * 8 + p) * 256 + d;
    float v = bf2f(part[idx]) + bf2f(part[idx + (size_t)4800 * 256]) +
              bf2f(part[idx + (size_t)2 * 4800 * 256]) + b;
    s += fmaxf(v, 0.f);
  }
  pvm[(size_t)row * 256 + d] = f2bf(s * 0.125f);
}

// ---------------------------------------------------------------------------
// 3x3 conv as GEMM, 512 threads (8 waves), BM=32, BN=128, BK=64,
// grid (256,2)=512 blocks.
__global__ __launch_bounds__(512) void k_conv3(const ushort_t* __restrict__ x2p,
                                               const ushort_t* __restrict__ wsm,
                                               const float* __restrict__ bsm,
                                               ushort_t* __restrict__ fcl) {
  __shared__ ushort_t As[32 * 72];
  __shared__ ushort_t Bs[128 * 72];
  int tid = threadIdx.x;
  int bm = blockIdx.x * 32, bn = blockIdx.y * 128;
  int w = tid >> 6, lane = tid & 63;
  int wm = (w & 1) * 16, wn = (w >> 1) * 32;   // wn in {0,32,64,96}
  int q = lane >> 4, ml = lane & 15;
  int sra = tid >> 4, sca = (tid & 15) * 4;    // 32 rows x 64K / 512 thr (short4)
  int srb = tid >> 2, scb = (tid & 3) * 16;    // 128 rows x 64K / 512 thr
  int sA = bm + sra;
  int b = sA >> 12, rem = sA & 4095;
  size_t pbase = ((size_t)(b * 66 + (rem >> 6)) * 66 + (rem & 63)) * 256;
  const ushort_t* Wg = wsm + (size_t)(bn + srb) * KP + scb;
  auto loadA = [&](int k0) {
    int ka = k0 + sca;
    int t9 = ka >> 8;
    int ky = t9 / 3, kx = t9 - ky * 3;
    return *(const short4_t*)(x2p + pbase + (size_t)(ky * 66 + kx) * 256 + (ka & 255));
  };
  f32x4 acc[2] = {};
  short4_t av = loadA(0);
  short8 wv0 = *(const short8*)(Wg);
  short8 wv1 = *(const short8*)(Wg + 8);
  for (int k0 = 0; k0 < KP; k0 += 64) {
    *(short4_t*)(As + sra * 72 + sca) = av;
    *(short8*)(Bs + srb * 72 + scb) = wv0;
    *(short8*)(Bs + srb * 72 + scb + 8) = wv1;
    __syncthreads();
    if (k0 + 64 < KP) {
      av = loadA(k0 + 64);
      wv0 = *(const short8*)(Wg + k0 + 64);
      wv1 = *(const short8*)(Wg + k0 + 72);
    }
#pragma unroll
    for (int h = 0; h < 2; ++h) {
      int kc = h * 32 + q * 8;
      short8 a = *(const short8*)(As + (wm + ml) * 72 + kc);
      short8 b0 = *(const short8*)(Bs + (wn + ml) * 72 + kc);
      short8 b1 = *(const short8*)(Bs + (wn + 16 + ml) * 72 + kc);
      acc[0] = __builtin_amdgcn_mfma_f32_16x16x32_bf16(a, b0, acc[0], 0, 0, 0);
      acc[1] = __builtin_amdgcn_mfma_f32_16x16x32_bf16(a, b1, acc[1], 0, 0, 0);
    }
    __syncthreads();
  }
#pragma unroll
  for (int j = 0; j < 2; ++j) {
    int cn = bn + wn + j * 16 + ml;
    float bsv = bsm[cn];
#pragma unroll
    for (int r = 0; r < 4; ++r) {
      int rm = bm + wm + q * 4 + r;
      fcl[(size_t)rm * 256 + cn] = f2bf(acc[j][r] + bsv);
    }
  }
}

// ---------------------------------------------------------------------------
// Fused box-update + r2ref + bilinear patch sampling. Block per (b,q,p).
// Gather phase remapped: lane = channel-quad (short4 8B loads), wave-group =
// patch subset (3/2/2/2 of 9 positions) -> 4x bytes/instruction.
__global__ __launch_bounds__(256) void k_sample(const ushort_t* __restrict__ fcl,
                                                const float* __restrict__ h1,
                                                const float* __restrict__ w_r2,
                                                const float* __restrict__ b_r2,
                                                const float* __restrict__ boxesIn,
                                                float* __restrict__ boxesOut,
                                                const float* __restrict__ hb,
                                                const float* __restrict__ w_b2,
                                                const float* __restrict__ b_b2,
                                                ushort_t* __restrict__ flat) {
  __shared__ float pr[8];
  __shared__ float bc2[2];
  __shared__ float nb2[2];
  int blk = blockIdx.x;
  int row = blk >> 3, p = blk & 7;
  int b = row / NQ;
  int tid = threadIdx.x;
  int w = tid >> 6, lane = tid & 63;
  if (hb) {
    float4 hv = *(const float4*)(hb + (size_t)row * 256 + lane * 4);
    float4 wv = *(const float4*)(w_b2 + (size_t)w * 256 + lane * 4);
    float aa = hv.x * wv.x + hv.y * wv.y + hv.z * wv.z + hv.w * wv.w;
#pragma unroll
    for (int s = 32; s > 0; s >>= 1) aa += __shfl_down(aa, s, 64);
    if (lane == 0) {
      aa += b_b2[w];
      float delta = 1.0f / (1.0f + expf(-aa));
      float v = boxesIn[row * 4 + w] + 0.1f * tanhf(delta - 0.5f);
      v = fminf(fmaxf(v, 0.f), 1.f);
      if (w < 2) nb2[w] = v;
      if (p == 0) boxesOut[row * 4 + w] = v;
    }
  } else if (tid < 2) {
    nb2[tid] = boxesIn[row * 4 + tid];
  }
  float h = h1[(size_t)row * 256 + tid];
  float px = h * w_r2[(size_t)(2 * p) * 256 + tid];
  float py = h * w_r2[(size_t)(2 * p + 1) * 256 + tid];
#pragma unroll
  for (int s = 32; s > 0; s >>= 1) {
    px += __shfl_down(px, s, 64);
    py += __shfl_down(py, s, 64);
  }
  if (lane == 0) { pr[w * 2] = px; pr[w * 2 + 1] = py; }
  __syncthreads();
  if (tid == 0) {
    float sx = pr[0] + pr[2] + pr[4] + pr[6] + b_r2[2 * p];
    float sy = pr[1] + pr[3] + pr[5] + pr[7] + b_r2[2 * p + 1];
    float rx = nb2[0] + 0.5f * tanhf(sx);
    float ry = nb2[1] + 0.5f * tanhf(sy);
    bc2[0] = fminf(fmaxf(rx, 0.f), 1.f);
    bc2[1] = fminf(fmaxf(ry, 0.f), 1.f);
  }
  __syncthreads();
  float rx = bc2[0], ry = bc2[1];
  const ushort_t* fb = fcl + (size_t)b * HW * DM;
  ushort_t* op = flat + (size_t)blk * KP;
  int c4 = (tid & 63) * 4;
  int g = tid >> 6;
  int p0 = (g == 0) ? 0 : (1 + 2 * g);   // 0,3,5,7
  int p1 = (g == 0) ? 3 : (3 + 2 * g);   // 3,5,7,9
  for (int p9 = p0; p9 < p1; ++p9) {
    int jy = (p9 >= 6) ? 2 : ((p9 >= 3) ? 1 : 0);
    int jx = p9 - jy * 3;
    float yy = (ry + (float)(jy - 1) * (1.0f / 64.0f)) * 63.0f;
    yy = fminf(fmaxf(yy, 0.f), 63.0f);
    float y0f = floorf(yy);
    float wy = yy - y0f;
    int y0 = (int)y0f;
    int y1 = min(y0 + 1, 63);
    float xx = (rx + (float)(jx - 1) * (1.0f / 64.0f)) * 63.0f;
    xx = fminf(fmaxf(xx, 0.f), 63.0f);
    float x0f = floorf(xx);
    float wx = xx - x0f;
    int x0 = (int)x0f;
    int x1 = min(x0 + 1, 63);
    short4_t v00 = *(const short4_t*)(fb + (y0 * 64 + x0) * DM + c4);
    short4_t v01 = *(const short4_t*)(fb + (y0 * 64 + x1) * DM + c4);
    short4_t v10 = *(const short4_t*)(fb + (y1 * 64 + x0) * DM + c4);
    short4_t v11 = *(const short4_t*)(fb + (y1 * 64 + x1) * DM + c4);
    short4_t ov;
#pragma unroll
    for (int jj = 0; jj < 4; ++jj) {
      float v = bf2f((ushort_t)v00[jj]) * (1.f - wx) * (1.f - wy) +
                bf2f((ushort_t)v01[jj]) * wx * (1.f - wy) +
                bf2f((ushort_t)v10[jj]) * (1.f - wx) * wy +
                bf2f((ushort_t)v11[jj]) * wx * wy;
      ov[jj] = (short)f2bf(v);
    }
    *(short4_t*)(op + p9 * DM + c4) = ov;
  }
}

// ---------------------------------------------------------------------------
// Attention in the Wp2-commuted basis, with the ctx@Wfuse update FUSED.
// (R10-proven form: LDS tree reductions, low VGPR.)
__global__ __launch_bounds__(256) void k_attn(const ushort_t* __restrict__ qt,
                                              const ushort_t* __restrict__ pvm,
                                              const ushort_t* __restrict__ wfT,
                                              const float* __restrict__ bfuse_l,
                                              float* __restrict__ queries,
                                              ushort_t* __restrict__ qbf) {
  __shared__ float qs[256];
  __shared__ float sc[512];
  __shared__ float red[256];
  __shared__ float pr4[1024];
  int row = blockIdx.x;
  int b = row / NQ;
  int tid = threadIdx.x;
  qs[tid] = bf2f(qt[(size_t)row * DM + tid]);
  __syncthreads();
  const ushort_t* kvB = pvm + (size_t)b * NQ * DM;
#pragma unroll
  for (int s2 = 0; s2 < 2; ++s2) {
    int k = tid + s2 * 256;
    float v = -1e30f;
    if (k < NQ) {
      const ushort_t* kp = kvB + (size_t)k * DM;
      float a = 0.f;
#pragma unroll
      for (int d = 0; d < 256; d += 8) {
        short8 k8 = *(const short8*)(kp + d);
        const float* qd = qs + d;
        a += bf2f((ushort_t)k8[0]) * qd[0];
        a += bf2f((ushort_t)k8[1]) * qd[1];
        a += bf2f((ushort_t)k8[2]) * qd[2];
        a += bf2f((ushort_t)k8[3]) * qd[3];
        a += bf2f((ushort_t)k8[4]) * qd[4];
        a += bf2f((ushort_t)k8[5]) * qd[5];
        a += bf2f((ushort_t)k8[6]) * qd[6];
        a += bf2f((ushort_t)k8[7]) * qd[7];
      }
      v = a * (1.0f / 16.0f);
    }
    sc[k] = v;
  }
  __syncthreads();
  red[tid] = fmaxf(sc[tid], sc[tid + 256]);
  __syncthreads();
  for (int st = 128; st > 0; st >>= 1) {
    if (tid < st) red[tid] = fmaxf(red[tid], red[tid + st]);
    __syncthreads();
  }
  float mx = red[0];
  __syncthreads();
  float e0 = (tid < NQ) ? expf(sc[tid] - mx) : 0.f;
  float e1 = (tid + 256 < NQ) ? expf(sc[tid + 256] - mx) : 0.f;
  sc[tid] = e0;
  sc[tid + 256] = e1;
  red[tid] = e0 + e1;
  __syncthreads();
  for (int st = 128; st > 0; st >>= 1) {
    if (tid < st) red[tid] += red[tid + st];
    __syncthreads();
  }
  float inv = 1.0f / red[0];
  __syncthreads();
  float acc = 0.f;
#pragma unroll 4
  for (int k = 0; k < NQ; ++k)
    acc += sc[k] * bf2f(kvB[(size_t)k * DM + tid]);
  // ctx stays in LDS (fp32), fused output projection follows.
  qs[tid] = acc * inv;
  __syncthreads();
  int oq = (tid & 63) * 4, dq = (tid >> 6) * 64;
  float a0 = 0.f, a1 = 0.f, a2 = 0.f, a3 = 0.f;
  const ushort_t* wp = wfT + (size_t)dq * 256 + oq;
#pragma unroll 8
  for (int dd = 0; dd < 64; ++dd) {
    float cc = qs[dq + dd];
    short4_t wv = *(const short4_t*)(wp + (size_t)dd * 256);
    a0 += cc * bf2f((ushort_t)wv[0]);
    a1 += cc * bf2f((ushort_t)wv[1]);
    a2 += cc * bf2f((ushort_t)wv[2]);
    a3 += cc * bf2f((ushort_t)wv[3]);
  }
  float* pb4 = pr4 + (tid >> 6) * 256 + oq;
  pb4[0] = a0; pb4[1] = a1; pb4[2] = a2; pb4[3] = a3;
  __syncthreads();
  float v = pr4[tid] + pr4[256 + tid] + pr4[512 + tid] + pr4[768 + tid] +
            bfuse_l[tid] + queries[(size_t)row * DM + tid];
  queries[(size_t)row * DM + tid] = v;
  qbf[(size_t)row * DM + tid] = f2bf(v);
}

// ---------------------------------------------------------------------------
// Final box update + fused final-output (launched ONCE, after the loop).
__global__ __launch_bounds__(256) void k_boxf(const float* __restrict__ hb,
                                              const float* __restrict__ w_b2,
                                              const float* __restrict__ b_b2,
                                              float* __restrict__ boxes,
                                              int last,
                                              const float* __restrict__ queries,
                                              const float* __restrict__ w_cls,
                                              const float* __restrict__ b_cls,
                                              float* __restrict__ out) {
  __shared__ float nb[4];
  int row = blockIdx.x;
  int tid = threadIdx.x;
  int j = tid >> 6, lane = tid & 63;
  float4 hv = *(const float4*)(hb + (size_t)row * 256 + lane * 4);
  float4 wv = *(const float4*)(w_b2 + (size_t)j * 256 + lane * 4);
  float aa = hv.x * wv.x + hv.y * wv.y + hv.z * wv.z + hv.w * wv.w;
#pragma unroll
  for (int s = 32; s > 0; s >>= 1) aa += __shfl_down(aa, s, 64);
  if (lane == 0) {
    aa += b_b2[j];
    float delta = 1.0f / (1.0f + expf(-aa));
    float v = boxes[row * 4 + j] + 0.1f * tanhf(delta - 0.5f);
    v = fminf(fmaxf(v, 0.f), 1.f);
    boxes[row * 4 + j] = v;
    nb[j] = v;
  }
  if (last) {
    __syncthreads();
    if (j == 0) {
      float4 qv = *(const float4*)(queries + (size_t)row * 256 + lane * 4);
      float4 cv = *(const float4*)(w_cls + lane * 4);
      float a2 = qv.x * cv.x + qv.y * cv.y + qv.z * cv.z + qv.w * cv.w;
#pragma unroll
      for (int s = 32; s > 0; s >>= 1) a2 += __shfl_down(a2, s, 64);
      if (lane == 0) out[row] = a2 + b_cls[0];
    } else if (j == 1 && lane < 4) {
      out[600 + row * 4 + lane] = nb[lane];
    }
  }
}

// ---------------------------------------------------------------------------
extern "C" void kernel_launch(void* const* d_in, const int* in_sizes, int n_in,
                              void* d_out, int out_size, void* d_ws, size_t ws_size,
                              hipStream_t stream) {
  const float* feat   = (const float*)d_in[0];
  const float* pb     = (const float*)d_in[1];
  const float* w_tf   = (const float*)d_in[2];
  const float* b_tf   = (const float*)d_in[3];
  const float* w_in   = (const float*)d_in[4];
  const float* b_in   = (const float*)d_in[5];
  const float* w_lat  = (const float*)d_in[6];
  const float* b_lat  = (const float*)d_in[7];
  const float* w_sm   = (const float*)d_in[8];
  const float* b_sm   = (const float*)d_in[9];
  const float* q_embed= (const float*)d_in[10];
  const float* q_pos  = (const float*)d_in[11];
  const float* Wq     = (const float*)d_in[12];
  const float* bq     = (const float*)d_in[13];
  const float* Wo     = (const float*)d_in[14];
  const float* bo     = (const float*)d_in[15];
  const float* Wp1    = (const float*)d_in[16];
  const float* bp1    = (const float*)d_in[17];
  const float* Wp2    = (const float*)d_in[18];
  const float* bp2    = (const float*)d_in[19];
  const float* w_r1   = (const float*)d_in[20];
  const float* b_r1   = (const float*)d_in[21];
  const float* w_r2   = (const float*)d_in[22];
  const float* b_r2   = (const float*)d_in[23];
  const float* w_b1   = (const float*)d_in[24];
  const float* b_b1   = (const float*)d_in[25];
  const float* w_b2   = (const float*)d_in[26];
  const float* b_b2   = (const float*)d_in[27];
  const float* w_cls  = (const float*)d_in[28];
  const float* b_cls  = (const float*)d_in[29];
  float* out = (float*)d_out;

  float* ws = (float*)d_ws;
  size_t off = 0;
  auto alloc = [&](size_t n) { float* p = ws + off; off += n; return p; };
  ushort_t* flat    = (ushort_t*)alloc(5529600);   // 4800 x 2304 bf16
  ushort_t* part    = (ushort_t*)alloc(1843200);   // 3 x 4800 x 256 bf16
  ushort_t* featT   = (ushort_t*)alloc(2097152);   // 8192 x 512 bf16
  ushort_t* x2p     = (ushort_t*)alloc(1115136);   // 2 x 66 x 66 x 256 bf16
  ushort_t* fcl     = (ushort_t*)alloc(1048576);   // 8192 x 256 bf16
  ushort_t* wcombT  = (ushort_t*)alloc(65536);     // 512 x 256 bf16 (transposed)
  ushort_t* wcomb2  = (ushort_t*)alloc(65536);     // 256 x 512 bf16 (wlat-composed)
  ushort_t* tct     = (ushort_t*)alloc(32768);     // 512 x 128 bf16
  ushort_t* win_bf  = (ushort_t*)alloc(16384);     // 256 x 128 bf16
  float*    bias2   = alloc(256);
  float*    ytab    = alloc(16384);                // 64 x 256 fp32
  float*    xtab    = alloc(16384);                // 64 x 256 fp32
  ushort_t* wlat_bf = (ushort_t*)alloc(32768);
  ushort_t* wsm_bf  = (ushort_t*)alloc(294912);
  ushort_t* wp1_bf  = (ushort_t*)alloc(1769472);   // 6 x 256 x 2304
  ushort_t* wb1_bf  = (ushort_t*)alloc(32768);
  ushort_t* wr1_bf  = (ushort_t*)alloc(32768);
  ushort_t* wqt_bf  = (ushort_t*)alloc(196608);    // composed Wqt
  ushort_t* wfuseT  = (ushort_t*)alloc(196608);    // composed (Wo@Wp2)^T
  float*    bqt     = alloc(1536);                 // 6 x 256
  float*    bfuse   = alloc(1536);                 // 6 x 256
  float* queries = alloc(153600);
  ushort_t* qbf  = (ushort_t*)alloc(76800);
  float* h1      = alloc(153600);
  ushort_t* qt   = (ushort_t*)alloc(76800);        // bf16 qt for attention
  float* hb      = alloc(153600);
  ushort_t* pvm  = (ushort_t*)alloc(76800);
  float* boxesA  = alloc(2400);
  float* boxesB  = alloc(2400);
  (void)ws_size; (void)in_sizes; (void)n_in; (void)out_size;

  // --- prep (includes featT transpose + bias2/Ytab/Xtab) ---
  k_prep<<<7046, 256, 0, stream>>>(w_in, w_lat, w_b1, w_r1, Wp1,
                                   win_bf, wlat_bf, wb1_bf, wr1_bf, wp1_bf,
                                   w_tf, tct, w_sm, wsm_bf,
                                   Wp2, Wo, bq, bp2, bo, bqt, bfuse,
                                   (uint4*)x2p, b_tf, b_in, b_lat,
                                   bias2, ytab, xtab,
                                   q_embed, q_pos, pb, queries, qbf, boxesA,
                                   feat, featT);
  // wcombT[k][d] = (win@tct)^T, then wcomb2[n][k] = wlat @ wcomb
  k_gemm_bf16<0, 8, 0><<<dim3(4, 8), 256, 0, stream>>>(win_bf, tct, nullptr, nullptr,
                                                       nullptr, wcombT, 256, 512, 128);
  k_gemm_bf16<0, 6, 0><<<dim3(4, 8), 256, 0, stream>>>(wlat_bf, wcombT, nullptr, nullptr,
                                                       nullptr, wcomb2, 256, 512, 256);
  k_wcompose<<<dim3(4, 4, 12), 256, 0, stream>>>(Wp2, Wq, Wo, wqt_bf, wfuseT);

  // --- backbone (lateral GEMM folded into feat2 via composed weights) ---
  k_feat2<<<dim3(256, 4), 256, 0, stream>>>(featT, wcomb2, bias2, ytab, xtab, x2p);
  k_conv3<<<dim3(256, 2), 512, 0, stream>>>(x2p, wsm_bf, b_sm, fcl);

  const int M6 = BB * NQ;                 // 600
  const int Mp = BB * NQ * NP;            // 4800
  dim3 g600w((M6 + 31) / 32, 8);          // (19,8)  BM=32
  dim3 g600m((M6 + 31) / 32, 12);         // (19,12) BM=32 merged N=768
  dim3 gsk(Mp / 64, 2, 3);                // (75,2,3) split-K BM=64 BN=128

  // layer-0: h1 = relu(q@w_r1+b_r1) | qt = bf16(q@Wqt[0]+bqt[0])
  k_gemm32<4><<<g600w, 256, 0, stream>>>(qbf, wr1_bf, b_r1, nullptr, h1,
                                         qt, M6, 256,
                                         wqt_bf, bqt, nullptr, nullptr);
  float* bcur = boxesA;
  float* bnext = boxesB;
  for (int l = 0; l < NL; ++l) {
    // fused box-update (l>0) + ref-point + sampling -> flat
    const float* hbp = (l == 0) ? nullptr : hb;
    k_sample<<<Mp, 256, 0, stream>>>(fcl, h1, w_r2, b_r2, bcur, bnext,
                                     hbp, w_b2, b_b2, flat);
    if (l > 0) { float* tmp = bcur; bcur = bnext; bnext = tmp; }
    // Wp1: split-K x3 (bf16 partials) + reduce(relu+pmean) -> pvm
    k_wp1_split<<<gsk, 512, 0, stream>>>(flat, wp1_bf + (size_t)l * 256 * KP, part);
    k_wp1_reduce<<<600, 256, 0, stream>>>(part, bp1 + (size_t)l * DM, pvm);
    // attention + fused output projection
    k_attn<<<M6, 256, 0, stream>>>(qt, pvm, wfuseT + (size_t)l * 65536,
                                   bfuse + l * 256, queries, qbf);
    // merged: hb=relu(q@w_b1) | h1=relu(q@w_r1) | qt=bf16(q@Wqt[l+1])
    int ln = (l + 1) % NL;
    k_gemm32<7><<<g600m, 256, 0, stream>>>(qbf, wb1_bf, b_b1, (const float*)qt,
                                           hb, (ushort_t*)h1, M6, 256,
                                           wr1_bf, b_r1,
                                           wqt_bf + (size_t)ln * 65536,
                                           bqt + ln * 256);
  }
  // final box update (#6) + logits/boxes output
  k_boxf<<<M6, 256, 0, stream>>>(hb, w_b2, b_b2, bcur, 1,
                                 queries, w_cls, b_cls, out);
}